// Round 8
// baseline (425.742 us; speedup 1.0000x reference)
//
#include <hip/hip_runtime.h>

// ---------------- problem constants ----------------
#define N_NODES  100000
#define N_EDGES  1600000
#define IN_DIM   128
#define HID      256
#define N_GRAPHS 256
#define ESHIFT   20.0f    // exp shift: final = exp(M-20)/sum(exp(h-20))
#define BSH      7        // dst-tile shift: bucket = dst >> 7 (128 nodes)
#define NB2      782      // ceil(100000/128)
#define XHB      12500    // x_to_h blocks in fused prep kernel

typedef _Float16 f16x8 __attribute__((ext_vector_type(8)));
typedef float f32x16 __attribute__((ext_vector_type(16)));
#define MFMA16(a, b, c) __builtin_amdgcn_mfma_f32_32x32x16_f16((a), (b), (c), 0, 0, 0)

// packed fp16 max (values are post-ReLU >= 0, finite)
#define PKMAX(a, b) asm("v_pk_max_f16 %0, %0, %1" : "+v"(a) : "v"(b))

#define BARX() __builtin_amdgcn_s_barrier()
#define WAITVM(N) asm volatile("s_waitcnt vmcnt(" #N ")" ::: "memory")

static __device__ __forceinline__ unsigned short f2h_bits(float f) {
    _Float16 h = (_Float16)f;
    return __builtin_bit_cast(unsigned short, h);
}
static __device__ __forceinline__ float h2f(unsigned short b) {
    return (float)__builtin_bit_cast(_Float16, b);
}

// ---------------- fused prep: x -> fp16 plane  +  bucket histogram ----------
__global__ __launch_bounds__(256) void prep_xh_count(
    const float* __restrict__ x, unsigned short* __restrict__ xh, int nx,
    const int* __restrict__ dst, int* __restrict__ btot, int E)
{
    __shared__ int sh[NB2];
    const int t = threadIdx.x;
    if ((int)blockIdx.x < XHB) {
        int i = (blockIdx.x * 256 + t) * 4;
        if (i < nx) {
            float4 v = *(const float4*)&x[i];
            ushort4 h;
            h.x = f2h_bits(v.x); h.y = f2h_bits(v.y);
            h.z = f2h_bits(v.z); h.w = f2h_bits(v.w);
            *(ushort4*)&xh[i] = h;
        }
        return;                      // block-uniform: no barrier divergence
    }
    for (int i = t; i < NB2; i += 256) sh[i] = 0;
    __syncthreads();
    int base = (blockIdx.x - XHB) * 4096 + t;
#pragma unroll
    for (int i = 0; i < 16; ++i) {
        int e = base + i * 256;
        if (e < E) atomicAdd(&sh[dst[e] >> BSH], 1);
    }
    __syncthreads();
    for (int i = t; i < NB2; i += 256)
        if (sh[i]) atomicAdd(&btot[i], sh[i]);
}

// ---------------- fused weight transpose + fp16 hi/lo split (1 launch) -----
static __device__ __forceinline__ void wsplit_seg(
    const float* __restrict__ Wa, const float* __restrict__ Wb, int K1,
    int K, int N, unsigned short* __restrict__ hi, unsigned short* __restrict__ lo,
    int idx)
{
    if (idx >= K * N) return;
    int k = idx / N, n = idx - k * N;
    float w = (k < K1) ? Wa[(size_t)k * N + n] : Wb[(size_t)(k - K1) * N + n];
    unsigned short h = f2h_bits(w);
    unsigned short l = f2h_bits(w - h2f(h));
    hi[(size_t)n * K + k] = h;
    lo[(size_t)n * K + k] = l;
}

__global__ __launch_bounds__(256) void w_split_all(
    const float* __restrict__ Wp, const float* __restrict__ Ws,
    const float* __restrict__ Wn, const float* __restrict__ W1,
    const float* __restrict__ W2, unsigned short* __restrict__ base)
{
    const int blk = blockIdx.x, tid = threadIdx.x;
    unsigned short* wpool_h = base;
    unsigned short* wpool_l = wpool_h + 16384;
    unsigned short* wsage_h = wpool_l + 16384;
    unsigned short* wsage_l = wsage_h + 65536;
    unsigned short* w1_h    = wsage_l + 65536;
    unsigned short* w1_l    = w1_h + 65536;
    unsigned short* w2_h    = w1_l + 65536;
    unsigned short* w2_l    = w2_h + 65536;
    if (blk < 64)
        wsplit_seg(Wp, Wp, 128, 128, 128, wpool_h, wpool_l, blk * 256 + tid);
    else if (blk < 320)
        wsplit_seg(Ws, Wn, 128, 256, 256, wsage_h, wsage_l, (blk - 64) * 256 + tid);
    else if (blk < 576)
        wsplit_seg(W1, W1, 256, 256, 256, w1_h, w1_l, (blk - 320) * 256 + tid);
    else
        wsplit_seg(W2, W2, 256, 256, 256, w2_h, w2_l, (blk - 576) * 256 + tid);
}

// ---------------- B-stationary streaming GEMM (K=256, N=256) ----------------
static __device__ __forceinline__ void stage_tile64(
    const unsigned short* __restrict__ A1, const unsigned short* __restrict__ A2,
    int K1, int M, int r0g, short* bufb, int wave, int lane)
{
    const int l5 = lane >> 5;
    const int s  = lane & 31;
#pragma unroll
    for (int i = 0; i < 4; ++i) {
        const int p    = wave * 4 + i;          // row-pair index 0..31
        const int rloc = 2 * p + l5;            // 0..63
        int row = r0g + rloc; if (row >= M) row = M - 1;
        const int c8 = ((s ^ ((2 * i + l5) & 7)) << 3);  // pre-swizzled src k
        const unsigned short* sp = (c8 < K1)
            ? A1 + (size_t)row * K1 + c8
            : A2 + (size_t)row * (256 - K1) + (c8 - K1);
        __builtin_amdgcn_global_load_lds(sp, bufb + p * 512, 16, 0, 0);
    }
}

__global__ __launch_bounds__(512, 2) void gemm_bstat(
    const unsigned short* __restrict__ A1, const unsigned short* __restrict__ A2,
    int K1,
    const unsigned short* __restrict__ Wh, const unsigned short* __restrict__ Wl,
    const float* __restrict__ bias, unsigned short* __restrict__ C,
    unsigned short* __restrict__ dummy, int M)
{
    __shared__ __align__(16) short buf[2][64][256];   // 64KB -> 2 blocks/CU

    const int tid = threadIdx.x, wave = tid >> 6, lane = tid & 63;
    const int lm = lane & 31, hib = lane >> 5;
    const int col = wave * 32 + lm;
    const int hi8 = hib * 8;

    f16x8 Bh[16], Bl[16];
#pragma unroll
    for (int k = 0; k < 16; ++k) {
        const size_t o = (size_t)col * 256 + k * 16 + hi8;
        Bh[k] = *(const f16x8*)(Wh + o);
        Bl[k] = *(const f16x8*)(Wl + o);
    }

    const int nt = (M + 63) >> 6;
    const int G = gridDim.x, b = blockIdx.x;
    const int q = nt / G, r = nt % G;
    const int t0  = b * q + (b < r ? b : r);
    const int ntl = q + (b < r ? 1 : 0);

    const int rq    = (lm >> 1) & 3;
    const int abase = lm * 512 + ((hib ^ (lm & 1)) << 4);
    const float bv  = bias[col];
    const int rb    = 4 * hib;

    stage_tile64(A1, A2, K1, M, t0 << 6, &buf[0][0][0], wave, lane);
    if (ntl > 1)
        stage_tile64(A1, A2, K1, M, (t0 + 1) << 6, &buf[1][0][0], wave, lane);

    for (int t = 0; t < ntl; ++t) {
        if (t == 0) { if (ntl > 1) WAITVM(4); else WAITVM(0); }
        else if (t + 1 < ntl) WAITVM(36);
        else WAITVM(32);
        BARX();

        f32x16 acc0, acc1;
#pragma unroll
        for (int i = 0; i < 16; ++i) { acc0[i] = 0.f; acc1[i] = 0.f; }
        const char* lb = (const char*)&buf[t & 1][0][0];
#pragma unroll
        for (int k = 0; k < 16; ++k) {
            const int koff = ((k ^ rq) << 5);
            f16x8 a0 = *(const f16x8*)(lb + abase + koff);
            f16x8 a1 = *(const f16x8*)(lb + abase + koff + 16384);
            acc0 = MFMA16(a0, Bh[k], acc0);
            acc1 = MFMA16(a1, Bh[k], acc1);
            acc0 = MFMA16(a0, Bl[k], acc0);
            acc1 = MFMA16(a1, Bl[k], acc1);
        }
        BARX();

        // prefetch first (HBM latency hides under store issue), then exactly
        // 32 stores (clamped rows -> dummy) so the in-flight count is fixed.
        if (t + 2 < ntl)
            stage_tile64(A1, A2, K1, M, (t0 + t + 2) << 6,
                         &buf[t & 1][0][0], wave, lane);
        const int r0g = (t0 + t) << 6;
#pragma unroll
        for (int reg = 0; reg < 16; ++reg) {
            const int rr0 = r0g + (reg & 3) + 8 * (reg >> 2) + rb;
            const int rr1 = rr0 + 32;
            unsigned short* d0 = (rr0 < M) ? C + (size_t)rr0 * 256 + col : dummy + tid;
            unsigned short* d1 = (rr1 < M) ? C + (size_t)rr1 * 256 + col : dummy + tid;
            *d0 = f2h_bits(fmaxf(acc0[reg] + bv, 0.f));
            *d1 = f2h_bits(fmaxf(acc1[reg] + bv, 0.f));
        }
    }
}

// ---------------- B-stationary GEMM0 (K=128, N=128) -------------------------
static __device__ __forceinline__ void stage_tile64_k128(
    const unsigned short* __restrict__ A, int M, int r0g,
    short* bufb, int wave, int lane)
{
#pragma unroll
    for (int p = 0; p < 2; ++p) {
        const int rl = p * 32 + wave * 4 + (lane >> 4);   // local row 0..63
        int row = r0g + rl; if (row >= M) row = M - 1;
        const int ch = (lane & 15) ^ (rl & 7);            // pre-swizzled chunk
        __builtin_amdgcn_global_load_lds(
            A + (size_t)row * 128 + ch * 8,
            bufb + p * 4096 + wave * 512, 16, 0, 0);
    }
}

__global__ __launch_bounds__(512, 2) void gemm_bstat128(
    const unsigned short* __restrict__ A,
    const unsigned short* __restrict__ Wh, const unsigned short* __restrict__ Wl,
    const float* __restrict__ bias, unsigned short* __restrict__ C,
    unsigned short* __restrict__ dummy, int M)
{
    __shared__ __align__(16) short buf[2][64][128];   // 32KB

    const int tid = threadIdx.x, wave = tid >> 6, lane = tid & 63;
    const int lm = lane & 31, hib = lane >> 5;
    const int colT = wave & 3;
    const int rw   = (wave >> 2) * 32;
    const int col  = colT * 32 + lm;

    f16x8 Bh[8], Bl[8];
#pragma unroll
    for (int k = 0; k < 8; ++k) {
        const size_t o = (size_t)col * 128 + k * 16 + hib * 8;
        Bh[k] = *(const f16x8*)(Wh + o);
        Bl[k] = *(const f16x8*)(Wl + o);
    }

    const int nt = (M + 63) >> 6;
    const int G = gridDim.x, b = blockIdx.x;
    const int q = nt / G, r = nt % G;
    const int t0  = b * q + (b < r ? b : r);
    const int ntl = q + (b < r ? 1 : 0);

    const int ch0 = hib ^ (lm & 7);        // read-side swizzle base
    const float bv = bias[col];

    stage_tile64_k128(A, M, t0 << 6, &buf[0][0][0], wave, lane);
    if (ntl > 1)
        stage_tile64_k128(A, M, (t0 + 1) << 6, &buf[1][0][0], wave, lane);

    for (int t = 0; t < ntl; ++t) {
        if (t == 0) { if (ntl > 1) WAITVM(2); else WAITVM(0); }
        else if (t + 1 < ntl) WAITVM(18);
        else WAITVM(16);
        BARX();

        f32x16 acc;
#pragma unroll
        for (int i = 0; i < 16; ++i) acc[i] = 0.f;
        const char* lb = (const char*)&buf[t & 1][0][0] + (rw + lm) * 256;
#pragma unroll
        for (int k = 0; k < 8; ++k) {
            f16x8 a = *(const f16x8*)(lb + (((2 * k) ^ ch0) << 4));
            acc = MFMA16(a, Bh[k], acc);
            acc = MFMA16(a, Bl[k], acc);
        }
        BARX();

        if (t + 2 < ntl)
            stage_tile64_k128(A, M, (t0 + t + 2) << 6,
                              &buf[t & 1][0][0], wave, lane);
        const int r0g = (t0 + t) << 6;
#pragma unroll
        for (int reg = 0; reg < 16; ++reg) {
            const int rr = r0g + rw + (reg & 3) + 8 * (reg >> 2) + 4 * hib;
            unsigned short* d = (rr < M) ? C + (size_t)rr * 128 + col : dummy + tid;
            *d = f2h_bits(fmaxf(acc[reg] + bv, 0.f));
        }
    }
}

// ---------------- B-stationary GEMM3 + fused softmax partials ---------------
// 4 LDS graph slots (8KB partials; 72KB total -> 2 blocks/CU). At grid 512
// each block spans ~3 tiles (~192 rows < 1 graph avg) so slot overflow to
// global atomics is rare.
static __device__ __forceinline__ void sm_flush(
    int run_g, float run_s, float run_m, int gfirst, int col,
    float* sS, int* sM, float* ps, float* pm)
{
    if (run_g < 0) return;
    int slot = run_g - gfirst;
    if (slot < 4) {
        atomicAdd(&sS[slot * 256 + col], run_s);
        atomicMax(&sM[slot * 256 + col], __float_as_int(run_m));
    } else {
        atomicAdd(&ps[(size_t)run_g * HID + col], run_s);
        atomicMax((int*)&pm[(size_t)run_g * HID + col], __float_as_int(run_m));
    }
}

__global__ __launch_bounds__(512, 2) void gemm_bstat_sm(
    const unsigned short* __restrict__ A,
    const unsigned short* __restrict__ Wh, const unsigned short* __restrict__ Wl,
    const float* __restrict__ bias, const int* __restrict__ gid,
    float* __restrict__ pm, float* __restrict__ ps, int M)
{
    __shared__ __align__(16) short buf[2][64][256];   // 64KB
    __shared__ float sS[4 * 256];                     // 4KB exp-sums
    __shared__ int   sM[4 * 256];                     // 4KB maxes

    const int tid = threadIdx.x, wave = tid >> 6, lane = tid & 63;
    const int lm = lane & 31, hib = lane >> 5;
    const int col = wave * 32 + lm;
    const int hi8 = hib * 8;

    for (int i = tid; i < 1024; i += 512) { sS[i] = 0.f; sM[i] = 0; }

    f16x8 Bh[16], Bl[16];
#pragma unroll
    for (int k = 0; k < 16; ++k) {
        const size_t o = (size_t)col * 256 + k * 16 + hi8;
        Bh[k] = *(const f16x8*)(Wh + o);
        Bl[k] = *(const f16x8*)(Wl + o);
    }

    const int nt = (M + 63) >> 6;
    const int G = gridDim.x, b = blockIdx.x;
    const int q = nt / G, r = nt % G;
    const int t0  = b * q + (b < r ? b : r);
    const int ntl = q + (b < r ? 1 : 0);

    const int rq    = (lm >> 1) & 3;
    const int abase = lm * 512 + ((hib ^ (lm & 1)) << 4);
    const float bv  = bias[col];
    const int rb    = 4 * hib;
    const int gfirst = gid[t0 << 6];

    stage_tile64(A, A, 256, M, t0 << 6, &buf[0][0][0], wave, lane);
    if (ntl > 1)
        stage_tile64(A, A, 256, M, (t0 + 1) << 6, &buf[1][0][0], wave, lane);

    int run_g = -1; float run_s = 0.f, run_m = 0.f;

    for (int t = 0; t < ntl; ++t) {
        if (t + 1 < ntl) WAITVM(4); else WAITVM(0);
        BARX();

        // issue the tile's gid load early; latency hides under MFMA loop
        const int r0g = (t0 + t) << 6;
        int gr = r0g + lane; if (gr >= M) gr = M - 1;
        int gv = gid[gr];
        asm volatile("" :: "v"(gv));     // pin issue point (rule 17)

        f32x16 acc0, acc1;
#pragma unroll
        for (int i = 0; i < 16; ++i) { acc0[i] = 0.f; acc1[i] = 0.f; }
        const char* lb = (const char*)&buf[t & 1][0][0];
#pragma unroll
        for (int k = 0; k < 16; ++k) {
            const int koff = ((k ^ rq) << 5);
            f16x8 a0 = *(const f16x8*)(lb + abase + koff);
            f16x8 a1 = *(const f16x8*)(lb + abase + koff + 16384);
            acc0 = MFMA16(a0, Bh[k], acc0);
            acc1 = MFMA16(a1, Bh[k], acc1);
            acc0 = MFMA16(a0, Bl[k], acc0);
            acc1 = MFMA16(a1, Bl[k], acc1);
        }
        BARX();

        // prefetch next-next tile, then drain gv (stage t+2 stays in flight)
        if (t + 2 < ntl) {
            stage_tile64(A, A, 256, M, (t0 + t + 2) << 6,
                         &buf[t & 1][0][0], wave, lane);
            WAITVM(4);
        } else {
            WAITVM(0);
        }

        const int gT0 = __shfl(gv, 0);
        const int gT1 = __shfl(gv, 63);
        if (gT0 == gT1) {
            // fast path: whole tile one graph (wave-uniform branch)
            if (gT0 != run_g) {
                sm_flush(run_g, run_s, run_m, gfirst, col, sS, sM, ps, pm);
                run_g = gT0; run_s = 0.f; run_m = 0.f;
            }
#pragma unroll
            for (int sub = 0; sub < 2; ++sub) {
                const f32x16& a = sub ? acc1 : acc0;
#pragma unroll
                for (int reg = 0; reg < 16; ++reg) {
                    const int rrow = r0g + sub * 32 + (reg & 3) + 8 * (reg >> 2) + rb;
                    float v = fmaxf(a[reg] + bv, 0.f);
                    bool ok = rrow < M;
                    run_s += ok ? __expf(v - ESHIFT) : 0.f;
                    run_m = ok ? fmaxf(run_m, v) : run_m;
                }
            }
        } else {
            // slow path: graph boundary inside tile; g via shfl (no VMEM)
#pragma unroll
            for (int sub = 0; sub < 2; ++sub) {
                const f32x16& a = sub ? acc1 : acc0;
#pragma unroll
                for (int reg = 0; reg < 16; ++reg) {
                    const int roff = sub * 32 + (reg & 3) + 8 * (reg >> 2) + rb;
                    const int rrow = r0g + roff;
                    int g = __shfl(gv, roff);
                    if (rrow >= M) continue;
                    float v = fmaxf(a[reg] + bv, 0.f);
                    if (g != run_g) {
                        sm_flush(run_g, run_s, run_m, gfirst, col, sS, sM, ps, pm);
                        run_g = g; run_s = 0.f; run_m = 0.f;
                    }
                    run_s += __expf(v - ESHIFT);
                    run_m = fmaxf(run_m, v);
                }
            }
        }
    }

    sm_flush(run_g, run_s, run_m, gfirst, col, sS, sM, ps, pm);
    __syncthreads();

    int lastrow = ((t0 + ntl) << 6) - 1; if (lastrow >= M) lastrow = M - 1;
    int span = gid[lastrow] - gfirst + 1; if (span > 4) span = 4;
    for (int i = tid; i < span * 256; i += 512) {
        float vs = sS[i];
        if (vs > 0.f) {
            int g = gfirst + (i >> 8), c = i & 255;
            atomicAdd(&ps[(size_t)g * HID + c], vs);
            atomicMax((int*)&pm[(size_t)g * HID + c], sM[i]);
        }
    }
}

// ---------------- edge pipeline: scan -> partition -> bucket sort -----------
__global__ __launch_bounds__(256) void scan_b(
    const int* __restrict__ btot, int* __restrict__ bstart,
    int* __restrict__ cursor, int total)
{
    __shared__ int sh[256];
    const int t = threadIdx.x;
    int a[4];
    int s = 0;
#pragma unroll
    for (int i = 0; i < 4; ++i) {
        int idx = t * 4 + i;
        a[i] = (idx < NB2) ? btot[idx] : 0;
        s += a[i];
    }
    sh[t] = s;
    __syncthreads();
    for (int off = 1; off < 256; off <<= 1) {
        int v = (t >= off) ? sh[t - off] : 0;
        __syncthreads();
        if (t >= off) sh[t] += v;
        __syncthreads();
    }
    int run = (t > 0) ? sh[t - 1] : 0;
#pragma unroll
    for (int i = 0; i < 4; ++i) {
        int idx = t * 4 + i;
        if (idx < NB2) { bstart[idx] = run; cursor[idx] = run; }
        run += a[i];
    }
    if (t == 0) bstart[NB2] = total;
}

__global__ __launch_bounds__(256) void part_scatter(
    const int* __restrict__ src, const int* __restrict__ dst,
    int* __restrict__ cursor, int2* __restrict__ pairs, int E)
{
    __shared__ int cnt[NB2], goff[NB2], fill[NB2];
    const int t = threadIdx.x;
    const int base = blockIdx.x * 4096;
    for (int i = t; i < NB2; i += 256) { cnt[i] = 0; fill[i] = 0; }
    __syncthreads();
    int myd[16];
#pragma unroll
    for (int i = 0; i < 16; ++i) {
        int e = base + t + i * 256;
        myd[i] = (e < E) ? dst[e] : -1;
        if (myd[i] >= 0) atomicAdd(&cnt[myd[i] >> BSH], 1);
    }
    __syncthreads();
    for (int i = t; i < NB2; i += 256)
        goff[i] = cnt[i] ? atomicAdd(&cursor[i], cnt[i]) : 0;
    __syncthreads();
#pragma unroll
    for (int i = 0; i < 16; ++i) {
        int e = base + t + i * 256;
        if (myd[i] >= 0) {
            int b = myd[i] >> BSH;
            int r = atomicAdd(&fill[b], 1);
            pairs[goff[b] + r] = make_int2(myd[i], src[e]);
        }
    }
}

__global__ __launch_bounds__(256) void bucket_sort(
    const int2* __restrict__ pairs, const int* __restrict__ bstart,
    int* __restrict__ csr_src, int* __restrict__ offs, int Nn, int E)
{
    __shared__ int cnt[128], off[128];
    const int b = blockIdx.x;
    const int t = threadIdx.x;
    const int lo = bstart[b], hi = bstart[b + 1];
    if (t < 128) cnt[t] = 0;
    __syncthreads();
    for (int e = lo + t; e < hi; e += 256)
        atomicAdd(&cnt[pairs[e].x & 127], 1);
    __syncthreads();
    if (t == 0) {
        int s = 0;
        for (int i = 0; i < 128; ++i) { off[i] = s; s += cnt[i]; }
    }
    __syncthreads();
    if (t < 128) {
        int node = (b << BSH) + t;
        if (node < Nn) offs[node] = lo + off[t];
        cnt[t] = off[t];          // reuse as fill cursor
    }
    if (b == NB2 - 1 && t == 0) offs[Nn] = E;
    __syncthreads();
    for (int e = lo + t; e < hi; e += 256) {
        int2 p = pairs[e];
        int r = atomicAdd(&cnt[p.x & 127], 1);
        csr_src[lo + r] = p.y;
    }
}

// ---------------- CSR max aggregation over fp16 m, one wave per node --------
// At its structural floor: random gather, fabric-limited (~3.8 TB/s L2-miss
// service, ~7.5 TB/s effective delivered). ILP probe (R6) moved it only -2us.
__global__ __launch_bounds__(256) void csr_max_agg_h(
    const unsigned short* __restrict__ m, const int* __restrict__ csr_src,
    const int* __restrict__ offs, unsigned short* __restrict__ neigh, int Nn)
{
    const int node = (blockIdx.x * 256 + threadIdx.x) >> 6;
    const int lane = threadIdx.x & 63;
    if (node >= Nn) return;
    const int e0  = offs[node];
    const int end = offs[node + 1];
    const char* mc = (const char*)m;

    uint4 a0 = make_uint4(0u, 0u, 0u, 0u);
    uint4 a1 = a0, a2 = a0, a3 = a0;
    if (end > e0) {
        const unsigned fo = (unsigned)(lane & 15) << 4;   // feature byte off
        const int sub = lane >> 4;                        // row slot 0..3
        for (int base = e0; base < end; base += 64) {
            int ee = base + lane;
            int sl = csr_src[ee < end ? ee : (end - 1)];  // coalesced, clamped
            int cnt = end - base; if (cnt > 64) cnt = 64;
            int iters = (cnt + 3) >> 2;                   // 1..16
            for (int j = 0; j < iters; j += 4) {
                int j1 = j + 1 < 16 ? j + 1 : 15;
                int j2 = j + 2 < 16 ? j + 2 : 15;
                int j3 = j + 3 < 16 ? j + 3 : 15;
                int s0 = __shfl(sl, (j  << 2) | sub);
                int s1 = __shfl(sl, (j1 << 2) | sub);
                int s2 = __shfl(sl, (j2 << 2) | sub);
                int s3 = __shfl(sl, (j3 << 2) | sub);
                uint4 v0 = *(const uint4*)(mc + (((unsigned)s0 << 8) | fo));
                uint4 v1 = *(const uint4*)(mc + (((unsigned)s1 << 8) | fo));
                uint4 v2 = *(const uint4*)(mc + (((unsigned)s2 << 8) | fo));
                uint4 v3 = *(const uint4*)(mc + (((unsigned)s3 << 8) | fo));
                PKMAX(a0.x, v0.x); PKMAX(a0.y, v0.y);
                PKMAX(a0.z, v0.z); PKMAX(a0.w, v0.w);
                PKMAX(a1.x, v1.x); PKMAX(a1.y, v1.y);
                PKMAX(a1.z, v1.z); PKMAX(a1.w, v1.w);
                PKMAX(a2.x, v2.x); PKMAX(a2.y, v2.y);
                PKMAX(a2.z, v2.z); PKMAX(a2.w, v2.w);
                PKMAX(a3.x, v3.x); PKMAX(a3.y, v3.y);
                PKMAX(a3.z, v3.z); PKMAX(a3.w, v3.w);
            }
        }
        // merge the 4 unroll accumulators
        PKMAX(a0.x, a1.x); PKMAX(a0.y, a1.y);
        PKMAX(a0.z, a1.z); PKMAX(a0.w, a1.w);
        PKMAX(a2.x, a3.x); PKMAX(a2.y, a3.y);
        PKMAX(a2.z, a3.z); PKMAX(a2.w, a3.w);
        PKMAX(a0.x, a2.x); PKMAX(a0.y, a2.y);
        PKMAX(a0.z, a2.z); PKMAX(a0.w, a2.w);
        // reduce the 4 row-substreams (lane>>4 groups): xor16 then xor32
        uint4 o;
        o.x = __shfl_xor(a0.x, 16); o.y = __shfl_xor(a0.y, 16);
        o.z = __shfl_xor(a0.z, 16); o.w = __shfl_xor(a0.w, 16);
        PKMAX(a0.x, o.x); PKMAX(a0.y, o.y);
        PKMAX(a0.z, o.z); PKMAX(a0.w, o.w);
        o.x = __shfl_xor(a0.x, 32); o.y = __shfl_xor(a0.y, 32);
        o.z = __shfl_xor(a0.z, 32); o.w = __shfl_xor(a0.w, 32);
        PKMAX(a0.x, o.x); PKMAX(a0.y, o.y);
        PKMAX(a0.z, o.z); PKMAX(a0.w, o.w);
    }
    if (lane < 16)
        *(uint4*)((char*)neigh + (((size_t)node << 8) | ((unsigned)lane << 4))) = a0;
}

// ---------------- merge: fm = exp(M-20)/S, then @ Wr + br ----------------
__global__ __launch_bounds__(256) void softmax_merge(
    const float* __restrict__ pm, const float* __restrict__ ps,
    const float* __restrict__ Wr, const float* __restrict__ brv,
    float* __restrict__ out)
{
    const int g = blockIdx.x;
    const int j = threadIdx.x;

    float M = pm[(size_t)g * HID + j];
    float S = ps[(size_t)g * HID + j];
    float fm = (S > 0.f) ? __expf(M - ESHIFT) / S : 0.f;

    float p0 = fm * Wr[j * 2 + 0];
    float p1 = fm * Wr[j * 2 + 1];
#pragma unroll
    for (int off = 32; off > 0; off >>= 1) {
        p0 += __shfl_down(p0, off);
        p1 += __shfl_down(p1, off);
    }
    __shared__ float red[8];
    int wv = j >> 6, ln = j & 63;
    if (ln == 0) { red[wv * 2] = p0; red[wv * 2 + 1] = p1; }
    __syncthreads();
    if (j == 0) out[g * 2 + 0] = red[0] + red[2] + red[4] + red[6] + brv[0];
    if (j == 1) out[g * 2 + 1] = red[1] + red[3] + red[5] + red[7] + brv[1];
}

// ---------------- launcher ----------------
extern "C" void kernel_launch(void* const* d_in, const int* in_sizes, int n_in,
                              void* d_out, int out_size, void* d_ws, size_t ws_size,
                              hipStream_t stream)
{
    const float* x      = (const float*)d_in[0];
    const float* W_pool = (const float*)d_in[1];
    const float* b_pool = (const float*)d_in[2];
    const float* W_self = (const float*)d_in[3];
    const float* W_neigh= (const float*)d_in[4];
    const float* b_sage = (const float*)d_in[5];
    const float* W1     = (const float*)d_in[6];
    const float* b1     = (const float*)d_in[7];
    const float* W2     = (const float*)d_in[8];
    const float* b2     = (const float*)d_in[9];
    const float* Wr     = (const float*)d_in[10];
    const float* br     = (const float*)d_in[11];
    const int*   src    = (const int*)d_in[12];
    const int*   dst    = (const int*)d_in[13];
    const int*   gid    = (const int*)d_in[14];

    const int Nn = N_NODES, E = N_EDGES;
    char* ws = (char*)d_ws;

    // ws layout (unchanged; pairs doubles as GEMM dummy-store sink, dead
    // after bucket_sort):
    unsigned short* xh    = (unsigned short*)(ws + 0);
    unsigned short* m_buf = (unsigned short*)(ws + 25600000);
    unsigned short* neigh = (unsigned short*)(ws + 51200000);
    int2*           pairs = (int2*)(ws + 76800000);
    int*            btot  = (int*)(ws + 89600000);
    int*            bstart= btot + NB2;
    int*            cursor= bstart + NB2 + 1;
    float*          pm    = (float*)(ws + 90000000);
    float*          ps    = pm + (size_t)N_GRAPHS * HID;
    int*            offs  = (int*)(ws + 91000000);
    int*            csr_src = (int*)(ws + 91500000);
    unsigned short* h1    = (unsigned short*)(ws + 102400000);
    unsigned short* h2    = (unsigned short*)(ws + 153600000);
    unsigned short* dummy = (unsigned short*)pairs;

    char* srcws = (char*)(void*)src;
    unsigned short* wpool_h = (unsigned short*)(srcws + 0);
    unsigned short* wpool_l = wpool_h + 128 * 128;
    unsigned short* wsage_h = wpool_l + 128 * 128;
    unsigned short* wsage_l = wsage_h + 256 * 256;
    unsigned short* w1_h    = wsage_l + 256 * 256;
    unsigned short* w1_l    = w1_h + 256 * 256;
    unsigned short* w2_h    = w1_l + 256 * 256;
    unsigned short* w2_l    = w2_h + 256 * 256;

    dim3 blk(256);
    const int pchunks = (E + 4095) / 4096;    // 391

    hipMemsetAsync(btot, 0, NB2 * sizeof(int), stream);
    hipMemsetAsync(pm, 0, (size_t)2 * N_GRAPHS * HID * sizeof(float), stream);

    // fused prep: x -> fp16 plane + bucket histogram (XHB + 391 blocks)
    prep_xh_count<<<dim3(XHB + pchunks), blk, 0, stream>>>(
        x, xh, Nn * IN_DIM, dst, btot, E);

    scan_b<<<dim3(1), blk, 0, stream>>>(btot, bstart, cursor, E);
    part_scatter<<<dim3(pchunks), blk, 0, stream>>>(src, dst, cursor, pairs, E);

    // src consumed by part_scatter: weight planes overwrite it now (1 launch)
    w_split_all<<<dim3(832), blk, 0, stream>>>(
        W_pool, W_self, W_neigh, W1, W2, (unsigned short*)srcws);

    bucket_sort<<<dim3(NB2), blk, 0, stream>>>(pairs, bstart, csr_src, offs, Nn, E);

    // GEMM0: m = relu(x @ W_pool + b_pool) -> fp16 [N,128] (B-stationary)
    gemm_bstat128<<<dim3(512), dim3(512), 0, stream>>>(
        xh, wpool_h, wpool_l, b_pool, m_buf, dummy, Nn);

    // neigh = segment-max of m
    csr_max_agg_h<<<dim3((Nn * 64 + 255) / 256), blk, 0, stream>>>(
        m_buf, csr_src, offs, neigh, Nn);

    // h1 = relu([x|neigh] @ [W_self;W_neigh] + b_sage) -> fp16 (B-stationary)
    gemm_bstat<<<dim3(512), dim3(512), 0, stream>>>(
        xh, neigh, 128, wsage_h, wsage_l, b_sage, h1, dummy, Nn);

    // h2 = relu(h1 @ W1 + b1) -> fp16 (B-stationary)
    gemm_bstat<<<dim3(512), dim3(512), 0, stream>>>(
        h1, h1, 256, w1_h, w1_l, b1, h2, dummy, Nn);

    // GEMM3 fused: softmax partials straight from the accumulators
    gemm_bstat_sm<<<dim3(512), dim3(512), 0, stream>>>(
        h2, w2_h, w2_l, b2, gid, pm, ps, Nn);

    // merge + final linear -> [256,2]
    softmax_merge<<<dim3(N_GRAPHS), blk, 0, stream>>>(pm, ps, Wr, br, (float*)d_out);
}

// Round 9
// 413.661 us; speedup vs baseline: 1.0292x; 1.0292x over previous
//
#include <hip/hip_runtime.h>

// ---------------- problem constants ----------------
#define N_NODES  100000
#define N_EDGES  1600000
#define IN_DIM   128
#define HID      256
#define N_GRAPHS 256
#define ESHIFT   20.0f    // exp shift: final = exp(M-20)/sum(exp(h-20))
#define BSH      7        // dst-tile shift: bucket = dst >> 7 (128 nodes)
#define NB2      782      // ceil(100000/128)
#define XHB      12500    // x_to_h blocks in fused prep kernel

typedef _Float16 f16x8 __attribute__((ext_vector_type(8)));
typedef float f32x16 __attribute__((ext_vector_type(16)));
#define MFMA16(a, b, c) __builtin_amdgcn_mfma_f32_32x32x16_f16((a), (b), (c), 0, 0, 0)

// packed fp16 max (values are post-ReLU >= 0, finite)
#define PKMAX(a, b) asm("v_pk_max_f16 %0, %0, %1" : "+v"(a) : "v"(b))

#define BARX() __builtin_amdgcn_s_barrier()
#define WAITVM(N) asm volatile("s_waitcnt vmcnt(" #N ")" ::: "memory")

static __device__ __forceinline__ unsigned short f2h_bits(float f) {
    _Float16 h = (_Float16)f;
    return __builtin_bit_cast(unsigned short, h);
}
static __device__ __forceinline__ float h2f(unsigned short b) {
    return (float)__builtin_bit_cast(_Float16, b);
}

// ---------------- fused prep: x -> fp16 plane  +  bucket histogram ----------
__global__ __launch_bounds__(256) void prep_xh_count(
    const float* __restrict__ x, unsigned short* __restrict__ xh, int nx,
    const int* __restrict__ dst, int* __restrict__ btot, int E)
{
    __shared__ int sh[NB2];
    const int t = threadIdx.x;
    if ((int)blockIdx.x < XHB) {
        int i = (blockIdx.x * 256 + t) * 4;
        if (i < nx) {
            float4 v = *(const float4*)&x[i];
            ushort4 h;
            h.x = f2h_bits(v.x); h.y = f2h_bits(v.y);
            h.z = f2h_bits(v.z); h.w = f2h_bits(v.w);
            *(ushort4*)&xh[i] = h;
        }
        return;                      // block-uniform: no barrier divergence
    }
    for (int i = t; i < NB2; i += 256) sh[i] = 0;
    __syncthreads();
    int base = (blockIdx.x - XHB) * 4096 + t;
#pragma unroll
    for (int i = 0; i < 16; ++i) {
        int e = base + i * 256;
        if (e < E) atomicAdd(&sh[dst[e] >> BSH], 1);
    }
    __syncthreads();
    for (int i = t; i < NB2; i += 256)
        if (sh[i]) atomicAdd(&btot[i], sh[i]);
}

// ---------------- fused weight transpose + fp16 hi/lo split (1 launch) -----
static __device__ __forceinline__ void wsplit_seg(
    const float* __restrict__ Wa, const float* __restrict__ Wb, int K1,
    int K, int N, unsigned short* __restrict__ hi, unsigned short* __restrict__ lo,
    int idx)
{
    if (idx >= K * N) return;
    int k = idx / N, n = idx - k * N;
    float w = (k < K1) ? Wa[(size_t)k * N + n] : Wb[(size_t)(k - K1) * N + n];
    unsigned short h = f2h_bits(w);
    unsigned short l = f2h_bits(w - h2f(h));
    hi[(size_t)n * K + k] = h;
    lo[(size_t)n * K + k] = l;
}

__global__ __launch_bounds__(256) void w_split_all(
    const float* __restrict__ Wp, const float* __restrict__ Ws,
    const float* __restrict__ Wn, const float* __restrict__ W1,
    const float* __restrict__ W2, unsigned short* __restrict__ base)
{
    const int blk = blockIdx.x, tid = threadIdx.x;
    unsigned short* wpool_h = base;
    unsigned short* wpool_l = wpool_h + 16384;
    unsigned short* wsage_h = wpool_l + 16384;
    unsigned short* wsage_l = wsage_h + 65536;
    unsigned short* w1_h    = wsage_l + 65536;
    unsigned short* w1_l    = w1_h + 65536;
    unsigned short* w2_h    = w1_l + 65536;
    unsigned short* w2_l    = w2_h + 65536;
    if (blk < 64)
        wsplit_seg(Wp, Wp, 128, 128, 128, wpool_h, wpool_l, blk * 256 + tid);
    else if (blk < 320)
        wsplit_seg(Ws, Wn, 128, 256, 256, wsage_h, wsage_l, (blk - 64) * 256 + tid);
    else if (blk < 576)
        wsplit_seg(W1, W1, 256, 256, 256, w1_h, w1_l, (blk - 320) * 256 + tid);
    else
        wsplit_seg(W2, W2, 256, 256, 256, w2_h, w2_l, (blk - 576) * 256 + tid);
}

// ---------------- B-stationary streaming GEMM (K=256, N=256) ----------------
// v2: 128-row x 256 A-tiles (2x the compute window per stage-wait; the 64-row
// version exposed ~0.5us of L2/HBM latency per tile at the locked 2 waves/SIMD
// occupancy). 8 waves, 4 accs/wave. Double-buffered 64KB tiles (128KB LDS).
// vmcnt: 8 loads + 64 stores per tile per wave; stores-BEFORE-prefetch so
// WAITVM(63) provably drains stage(t) while keeping stage(t+1) in flight
// (64 stores + 8 loads younger = 72 > 63).
static __device__ __forceinline__ void stage_tile128(
    const unsigned short* __restrict__ A1, const unsigned short* __restrict__ A2,
    int K1, int M, int r0g, short* bufb, int wave, int lane)
{
    const int l5 = lane >> 5;
    const int s  = lane & 31;
#pragma unroll
    for (int i = 0; i < 8; ++i) {
        const int p    = wave * 8 + i;          // row-pair index 0..63
        const int rloc = 2 * p + l5;            // 0..127
        int row = r0g + rloc; if (row >= M) row = M - 1;
        const int c8 = ((s ^ ((2 * i + l5) & 7)) << 3);  // pre-swizzled src k
        const unsigned short* sp = (c8 < K1)
            ? A1 + (size_t)row * K1 + c8
            : A2 + (size_t)row * (256 - K1) + (c8 - K1);
        __builtin_amdgcn_global_load_lds(sp, bufb + p * 512, 16, 0, 0);
    }
}

__global__ __launch_bounds__(512, 2) void gemm_bstat(
    const unsigned short* __restrict__ A1, const unsigned short* __restrict__ A2,
    int K1,
    const unsigned short* __restrict__ Wh, const unsigned short* __restrict__ Wl,
    const float* __restrict__ bias, unsigned short* __restrict__ C,
    unsigned short* __restrict__ dummy, int M)
{
    __shared__ __align__(16) short buf[2][128][256];   // 128KB

    const int tid = threadIdx.x, wave = tid >> 6, lane = tid & 63;
    const int lm = lane & 31, hib = lane >> 5;
    const int col = wave * 32 + lm;
    const int hi8 = hib * 8;

    f16x8 Bh[16], Bl[16];
#pragma unroll
    for (int k = 0; k < 16; ++k) {
        const size_t o = (size_t)col * 256 + k * 16 + hi8;
        Bh[k] = *(const f16x8*)(Wh + o);
        Bl[k] = *(const f16x8*)(Wl + o);
    }

    const int nt = (M + 127) >> 7;
    const int G = gridDim.x, b = blockIdx.x;
    const int q = nt / G, r = nt % G;
    const int t0  = b * q + (b < r ? b : r);
    const int ntl = q + (b < r ? 1 : 0);

    const int rq    = (lm >> 1) & 3;
    const int abase = lm * 512 + ((hib ^ (lm & 1)) << 4);
    const float bv  = bias[col];
    const int rb    = 4 * hib;

    if (ntl <= 0) return;
    stage_tile128(A1, A2, K1, M, t0 << 7, &buf[0][0][0], wave, lane);
    if (ntl > 1)
        stage_tile128(A1, A2, K1, M, (t0 + 1) << 7, &buf[1][0][0], wave, lane);

    for (int t = 0; t < ntl; ++t) {
        if (t == 0) { if (ntl > 1) WAITVM(8); else WAITVM(0); }
        else WAITVM(63);
        BARX();

        f32x16 acc0, acc1, acc2, acc3;
#pragma unroll
        for (int i = 0; i < 16; ++i) {
            acc0[i] = 0.f; acc1[i] = 0.f; acc2[i] = 0.f; acc3[i] = 0.f;
        }
        const char* lb = (const char*)&buf[t & 1][0][0];
#pragma unroll
        for (int k = 0; k < 16; ++k) {
            const int koff = ((k ^ rq) << 5);
            f16x8 a0 = *(const f16x8*)(lb + abase + koff);
            f16x8 a1 = *(const f16x8*)(lb + abase + koff + 16384);
            f16x8 a2 = *(const f16x8*)(lb + abase + koff + 32768);
            f16x8 a3 = *(const f16x8*)(lb + abase + koff + 49152);
            acc0 = MFMA16(a0, Bh[k], acc0);
            acc1 = MFMA16(a1, Bh[k], acc1);
            acc2 = MFMA16(a2, Bh[k], acc2);
            acc3 = MFMA16(a3, Bh[k], acc3);
            acc0 = MFMA16(a0, Bl[k], acc0);
            acc1 = MFMA16(a1, Bl[k], acc1);
            acc2 = MFMA16(a2, Bl[k], acc2);
            acc3 = MFMA16(a3, Bl[k], acc3);
        }
        BARX();

        // epilogue: exactly 64 stores (clamped rows -> dummy), THEN prefetch
        // (stores-first keeps stage(t+1) inside the youngest-63 window).
        const int r0g = (t0 + t) << 7;
#pragma unroll
        for (int j = 0; j < 4; ++j) {
            const f32x16& a = j == 0 ? acc0 : (j == 1 ? acc1 : (j == 2 ? acc2 : acc3));
#pragma unroll
            for (int reg = 0; reg < 16; ++reg) {
                const int rr = r0g + j * 32 + (reg & 3) + 8 * (reg >> 2) + rb;
                unsigned short* d = (rr < M) ? C + (size_t)rr * 256 + col : dummy + tid;
                *d = f2h_bits(fmaxf(a[reg] + bv, 0.f));
            }
        }
        if (t + 2 < ntl)
            stage_tile128(A1, A2, K1, M, (t0 + t + 2) << 7,
                          &buf[t & 1][0][0], wave, lane);
    }
}

// ---------------- B-stationary GEMM0 (K=128, N=128) -------------------------
static __device__ __forceinline__ void stage_tile64_k128(
    const unsigned short* __restrict__ A, int M, int r0g,
    short* bufb, int wave, int lane)
{
#pragma unroll
    for (int p = 0; p < 2; ++p) {
        const int rl = p * 32 + wave * 4 + (lane >> 4);   // local row 0..63
        int row = r0g + rl; if (row >= M) row = M - 1;
        const int ch = (lane & 15) ^ (rl & 7);            // pre-swizzled chunk
        __builtin_amdgcn_global_load_lds(
            A + (size_t)row * 128 + ch * 8,
            bufb + p * 4096 + wave * 512, 16, 0, 0);
    }
}

__global__ __launch_bounds__(512, 2) void gemm_bstat128(
    const unsigned short* __restrict__ A,
    const unsigned short* __restrict__ Wh, const unsigned short* __restrict__ Wl,
    const float* __restrict__ bias, unsigned short* __restrict__ C,
    unsigned short* __restrict__ dummy, int M)
{
    __shared__ __align__(16) short buf[2][64][128];   // 32KB

    const int tid = threadIdx.x, wave = tid >> 6, lane = tid & 63;
    const int lm = lane & 31, hib = lane >> 5;
    const int colT = wave & 3;
    const int rw   = (wave >> 2) * 32;
    const int col  = colT * 32 + lm;

    f16x8 Bh[8], Bl[8];
#pragma unroll
    for (int k = 0; k < 8; ++k) {
        const size_t o = (size_t)col * 128 + k * 16 + hib * 8;
        Bh[k] = *(const f16x8*)(Wh + o);
        Bl[k] = *(const f16x8*)(Wl + o);
    }

    const int nt = (M + 63) >> 6;
    const int G = gridDim.x, b = blockIdx.x;
    const int q = nt / G, r = nt % G;
    const int t0  = b * q + (b < r ? b : r);
    const int ntl = q + (b < r ? 1 : 0);

    const int ch0 = hib ^ (lm & 7);        // read-side swizzle base
    const float bv = bias[col];

    stage_tile64_k128(A, M, t0 << 6, &buf[0][0][0], wave, lane);
    if (ntl > 1)
        stage_tile64_k128(A, M, (t0 + 1) << 6, &buf[1][0][0], wave, lane);

    for (int t = 0; t < ntl; ++t) {
        if (t == 0) { if (ntl > 1) WAITVM(2); else WAITVM(0); }
        else if (t + 1 < ntl) WAITVM(18);
        else WAITVM(16);
        BARX();

        f32x16 acc;
#pragma unroll
        for (int i = 0; i < 16; ++i) acc[i] = 0.f;
        const char* lb = (const char*)&buf[t & 1][0][0] + (rw + lm) * 256;
#pragma unroll
        for (int k = 0; k < 8; ++k) {
            f16x8 a = *(const f16x8*)(lb + (((2 * k) ^ ch0) << 4));
            acc = MFMA16(a, Bh[k], acc);
            acc = MFMA16(a, Bl[k], acc);
        }
        BARX();

        if (t + 2 < ntl)
            stage_tile64_k128(A, M, (t0 + t + 2) << 6,
                              &buf[t & 1][0][0], wave, lane);
        const int r0g = (t0 + t) << 6;
#pragma unroll
        for (int reg = 0; reg < 16; ++reg) {
            const int rr = r0g + rw + (reg & 3) + 8 * (reg >> 2) + 4 * hib;
            unsigned short* d = (rr < M) ? C + (size_t)rr * 128 + col : dummy + tid;
            *d = f2h_bits(fmaxf(acc[reg] + bv, 0.f));
        }
    }
}

// ---------------- B-stationary GEMM3 + fused softmax partials ---------------
static __device__ __forceinline__ void sm_flush(
    int run_g, float run_s, float run_m, int gfirst, int col,
    float* sS, int* sM, float* ps, float* pm)
{
    if (run_g < 0) return;
    int slot = run_g - gfirst;
    if (slot < 8) {
        atomicAdd(&sS[slot * 256 + col], run_s);
        atomicMax(&sM[slot * 256 + col], __float_as_int(run_m));
    } else {
        atomicAdd(&ps[(size_t)run_g * HID + col], run_s);
        atomicMax((int*)&pm[(size_t)run_g * HID + col], __float_as_int(run_m));
    }
}

__global__ __launch_bounds__(512, 2) void gemm_bstat_sm(
    const unsigned short* __restrict__ A,
    const unsigned short* __restrict__ Wh, const unsigned short* __restrict__ Wl,
    const float* __restrict__ bias, const int* __restrict__ gid,
    float* __restrict__ pm, float* __restrict__ ps, int M)
{
    __shared__ __align__(16) short buf[2][128][256];  // 128KB
    __shared__ float sS[8 * 256];                     // 8KB exp-sums
    __shared__ int   sM[8 * 256];                     // 8KB maxes

    const int tid = threadIdx.x, wave = tid >> 6, lane = tid & 63;
    const int lm = lane & 31, hib = lane >> 5;
    const int col = wave * 32 + lm;
    const int hi8 = hib * 8;

    for (int i = tid; i < 2048; i += 512) { sS[i] = 0.f; sM[i] = 0; }

    f16x8 Bh[16], Bl[16];
#pragma unroll
    for (int k = 0; k < 16; ++k) {
        const size_t o = (size_t)col * 256 + k * 16 + hi8;
        Bh[k] = *(const f16x8*)(Wh + o);
        Bl[k] = *(const f16x8*)(Wl + o);
    }

    const int nt = (M + 127) >> 7;
    const int G = gridDim.x, b = blockIdx.x;
    const int q = nt / G, r = nt % G;
    const int t0  = b * q + (b < r ? b : r);
    const int ntl = q + (b < r ? 1 : 0);

    const int rq    = (lm >> 1) & 3;
    const int abase = lm * 512 + ((hib ^ (lm & 1)) << 4);
    const float bv  = bias[col];
    const int rb    = 4 * hib;

    if (ntl <= 0) { __syncthreads(); return; }
    const int gfirst = gid[t0 << 7];

    stage_tile128(A, A, 256, M, t0 << 7, &buf[0][0][0], wave, lane);
    if (ntl > 1)
        stage_tile128(A, A, 256, M, (t0 + 1) << 7, &buf[1][0][0], wave, lane);

    int run_g = -1; float run_s = 0.f, run_m = 0.f;

    for (int t = 0; t < ntl; ++t) {
        if (t == 0) { if (ntl > 1) WAITVM(8); else WAITVM(0); }
        else WAITVM(8);              // stage(t) drained by epi(t-1)'s wait
        BARX();

        // issue the tile's gid loads early; latency hides under MFMA loop
        const int r0g = (t0 + t) << 7;
        int gr0 = r0g + lane;       if (gr0 >= M) gr0 = M - 1;
        int gr1 = r0g + 64 + lane;  if (gr1 >= M) gr1 = M - 1;
        int gv0 = gid[gr0];
        int gv1 = gid[gr1];
        asm volatile("" :: "v"(gv0), "v"(gv1));   // pin issue point

        f32x16 acc0, acc1, acc2, acc3;
#pragma unroll
        for (int i = 0; i < 16; ++i) {
            acc0[i] = 0.f; acc1[i] = 0.f; acc2[i] = 0.f; acc3[i] = 0.f;
        }
        const char* lb = (const char*)&buf[t & 1][0][0];
#pragma unroll
        for (int k = 0; k < 16; ++k) {
            const int koff = ((k ^ rq) << 5);
            f16x8 a0 = *(const f16x8*)(lb + abase + koff);
            f16x8 a1 = *(const f16x8*)(lb + abase + koff + 16384);
            f16x8 a2 = *(const f16x8*)(lb + abase + koff + 32768);
            f16x8 a3 = *(const f16x8*)(lb + abase + koff + 49152);
            acc0 = MFMA16(a0, Bh[k], acc0);
            acc1 = MFMA16(a1, Bh[k], acc1);
            acc2 = MFMA16(a2, Bh[k], acc2);
            acc3 = MFMA16(a3, Bh[k], acc3);
            acc0 = MFMA16(a0, Bl[k], acc0);
            acc1 = MFMA16(a1, Bl[k], acc1);
            acc2 = MFMA16(a2, Bl[k], acc2);
            acc3 = MFMA16(a3, Bl[k], acc3);
        }
        BARX();

        // prefetch next-next tile, then drain gv (stage t+2 stays in flight)
        if (t + 2 < ntl) {
            stage_tile128(A, A, 256, M, (t0 + t + 2) << 7,
                          &buf[t & 1][0][0], wave, lane);
            WAITVM(8);
        } else {
            WAITVM(0);
        }

        const int gT0 = __shfl(gv0, 0);
        const int gT1 = __shfl(gv1, 63);
        if (gT0 == gT1) {
            // fast path: whole 128-row tile one graph (wave-uniform branch)
            if (gT0 != run_g) {
                sm_flush(run_g, run_s, run_m, gfirst, col, sS, sM, ps, pm);
                run_g = gT0; run_s = 0.f; run_m = 0.f;
            }
#pragma unroll
            for (int j = 0; j < 4; ++j) {
                const f32x16& a = j == 0 ? acc0 : (j == 1 ? acc1 : (j == 2 ? acc2 : acc3));
#pragma unroll
                for (int reg = 0; reg < 16; ++reg) {
                    const int rrow = r0g + j * 32 + (reg & 3) + 8 * (reg >> 2) + rb;
                    float v = fmaxf(a[reg] + bv, 0.f);
                    bool ok = rrow < M;
                    run_s += ok ? __expf(v - ESHIFT) : 0.f;
                    run_m = ok ? fmaxf(run_m, v) : run_m;
                }
            }
        } else {
            // slow path: graph boundary inside tile; g via shfl (no VMEM)
#pragma unroll
            for (int j = 0; j < 4; ++j) {
                const f32x16& a = j == 0 ? acc0 : (j == 1 ? acc1 : (j == 2 ? acc2 : acc3));
#pragma unroll
                for (int reg = 0; reg < 16; ++reg) {
                    const int roff = j * 32 + (reg & 3) + 8 * (reg >> 2) + rb;
                    const int rrow = r0g + roff;
                    int g = (j < 2) ? __shfl(gv0, roff) : __shfl(gv1, roff - 64);
                    if (rrow >= M) continue;
                    float v = fmaxf(a[reg] + bv, 0.f);
                    if (g != run_g) {
                        sm_flush(run_g, run_s, run_m, gfirst, col, sS, sM, ps, pm);
                        run_g = g; run_s = 0.f; run_m = 0.f;
                    }
                    run_s += __expf(v - ESHIFT);
                    run_m = fmaxf(run_m, v);
                }
            }
        }
    }

    sm_flush(run_g, run_s, run_m, gfirst, col, sS, sM, ps, pm);
    __syncthreads();

    int lastrow = ((t0 + ntl) << 7) - 1; if (lastrow >= M) lastrow = M - 1;
    int span = gid[lastrow] - gfirst + 1; if (span > 8) span = 8;
    for (int i = tid; i < span * 256; i += 512) {
        float vs = sS[i];
        if (vs > 0.f) {
            int g = gfirst + (i >> 8), c = i & 255;
            atomicAdd(&ps[(size_t)g * HID + c], vs);
            atomicMax((int*)&pm[(size_t)g * HID + c], sM[i]);
        }
    }
}

// ---------------- edge pipeline: scan -> partition -> bucket sort -----------
__global__ __launch_bounds__(256) void scan_b(
    const int* __restrict__ btot, int* __restrict__ bstart,
    int* __restrict__ cursor, int total)
{
    __shared__ int sh[256];
    const int t = threadIdx.x;
    int a[4];
    int s = 0;
#pragma unroll
    for (int i = 0; i < 4; ++i) {
        int idx = t * 4 + i;
        a[i] = (idx < NB2) ? btot[idx] : 0;
        s += a[i];
    }
    sh[t] = s;
    __syncthreads();
    for (int off = 1; off < 256; off <<= 1) {
        int v = (t >= off) ? sh[t - off] : 0;
        __syncthreads();
        if (t >= off) sh[t] += v;
        __syncthreads();
    }
    int run = (t > 0) ? sh[t - 1] : 0;
#pragma unroll
    for (int i = 0; i < 4; ++i) {
        int idx = t * 4 + i;
        if (idx < NB2) { bstart[idx] = run; cursor[idx] = run; }
        run += a[i];
    }
    if (t == 0) bstart[NB2] = total;
}

__global__ __launch_bounds__(256) void part_scatter(
    const int* __restrict__ src, const int* __restrict__ dst,
    int* __restrict__ cursor, int2* __restrict__ pairs, int E)
{
    __shared__ int cnt[NB2], goff[NB2], fill[NB2];
    const int t = threadIdx.x;
    const int base = blockIdx.x * 4096;
    for (int i = t; i < NB2; i += 256) { cnt[i] = 0; fill[i] = 0; }
    __syncthreads();
    int myd[16];
#pragma unroll
    for (int i = 0; i < 16; ++i) {
        int e = base + t + i * 256;
        myd[i] = (e < E) ? dst[e] : -1;
        if (myd[i] >= 0) atomicAdd(&cnt[myd[i] >> BSH], 1);
    }
    __syncthreads();
    for (int i = t; i < NB2; i += 256)
        goff[i] = cnt[i] ? atomicAdd(&cursor[i], cnt[i]) : 0;
    __syncthreads();
#pragma unroll
    for (int i = 0; i < 16; ++i) {
        int e = base + t + i * 256;
        if (myd[i] >= 0) {
            int b = myd[i] >> BSH;
            int r = atomicAdd(&fill[b], 1);
            pairs[goff[b] + r] = make_int2(myd[i], src[e]);
        }
    }
}

__global__ __launch_bounds__(256) void bucket_sort(
    const int2* __restrict__ pairs, const int* __restrict__ bstart,
    int* __restrict__ csr_src, int* __restrict__ offs, int Nn, int E)
{
    __shared__ int cnt[128], off[128];
    const int b = blockIdx.x;
    const int t = threadIdx.x;
    const int lo = bstart[b], hi = bstart[b + 1];
    if (t < 128) cnt[t] = 0;
    __syncthreads();
    for (int e = lo + t; e < hi; e += 256)
        atomicAdd(&cnt[pairs[e].x & 127], 1);
    __syncthreads();
    if (t == 0) {
        int s = 0;
        for (int i = 0; i < 128; ++i) { off[i] = s; s += cnt[i]; }
    }
    __syncthreads();
    if (t < 128) {
        int node = (b << BSH) + t;
        if (node < Nn) offs[node] = lo + off[t];
        cnt[t] = off[t];          // reuse as fill cursor
    }
    if (b == NB2 - 1 && t == 0) offs[Nn] = E;
    __syncthreads();
    for (int e = lo + t; e < hi; e += 256) {
        int2 p = pairs[e];
        int r = atomicAdd(&cnt[p.x & 127], 1);
        csr_src[lo + r] = p.y;
    }
}

// ---------------- CSR max aggregation over fp16 m, one wave per node --------
// At its structural floor: random gather, fabric-limited (~3.8 TB/s L2-miss
// service, ~7.5 TB/s effective delivered). ILP probe (R6) moved it only -2us.
__global__ __launch_bounds__(256) void csr_max_agg_h(
    const unsigned short* __restrict__ m, const int* __restrict__ csr_src,
    const int* __restrict__ offs, unsigned short* __restrict__ neigh, int Nn)
{
    const int node = (blockIdx.x * 256 + threadIdx.x) >> 6;
    const int lane = threadIdx.x & 63;
    if (node >= Nn) return;
    const int e0  = offs[node];
    const int end = offs[node + 1];
    const char* mc = (const char*)m;

    uint4 a0 = make_uint4(0u, 0u, 0u, 0u);
    uint4 a1 = a0, a2 = a0, a3 = a0;
    if (end > e0) {
        const unsigned fo = (unsigned)(lane & 15) << 4;   // feature byte off
        const int sub = lane >> 4;                        // row slot 0..3
        for (int base = e0; base < end; base += 64) {
            int ee = base + lane;
            int sl = csr_src[ee < end ? ee : (end - 1)];  // coalesced, clamped
            int cnt = end - base; if (cnt > 64) cnt = 64;
            int iters = (cnt + 3) >> 2;                   // 1..16
            for (int j = 0; j < iters; j += 4) {
                int j1 = j + 1 < 16 ? j + 1 : 15;
                int j2 = j + 2 < 16 ? j + 2 : 15;
                int j3 = j + 3 < 16 ? j + 3 : 15;
                int s0 = __shfl(sl, (j  << 2) | sub);
                int s1 = __shfl(sl, (j1 << 2) | sub);
                int s2 = __shfl(sl, (j2 << 2) | sub);
                int s3 = __shfl(sl, (j3 << 2) | sub);
                uint4 v0 = *(const uint4*)(mc + (((unsigned)s0 << 8) | fo));
                uint4 v1 = *(const uint4*)(mc + (((unsigned)s1 << 8) | fo));
                uint4 v2 = *(const uint4*)(mc + (((unsigned)s2 << 8) | fo));
                uint4 v3 = *(const uint4*)(mc + (((unsigned)s3 << 8) | fo));
                PKMAX(a0.x, v0.x); PKMAX(a0.y, v0.y);
                PKMAX(a0.z, v0.z); PKMAX(a0.w, v0.w);
                PKMAX(a1.x, v1.x); PKMAX(a1.y, v1.y);
                PKMAX(a1.z, v1.z); PKMAX(a1.w, v1.w);
                PKMAX(a2.x, v2.x); PKMAX(a2.y, v2.y);
                PKMAX(a2.z, v2.z); PKMAX(a2.w, v2.w);
                PKMAX(a3.x, v3.x); PKMAX(a3.y, v3.y);
                PKMAX(a3.z, v3.z); PKMAX(a3.w, v3.w);
            }
        }
        // merge the 4 unroll accumulators
        PKMAX(a0.x, a1.x); PKMAX(a0.y, a1.y);
        PKMAX(a0.z, a1.z); PKMAX(a0.w, a1.w);
        PKMAX(a2.x, a3.x); PKMAX(a2.y, a3.y);
        PKMAX(a2.z, a3.z); PKMAX(a2.w, a3.w);
        PKMAX(a0.x, a2.x); PKMAX(a0.y, a2.y);
        PKMAX(a0.z, a2.z); PKMAX(a0.w, a2.w);
        // reduce the 4 row-substreams (lane>>4 groups): xor16 then xor32
        uint4 o;
        o.x = __shfl_xor(a0.x, 16); o.y = __shfl_xor(a0.y, 16);
        o.z = __shfl_xor(a0.z, 16); o.w = __shfl_xor(a0.w, 16);
        PKMAX(a0.x, o.x); PKMAX(a0.y, o.y);
        PKMAX(a0.z, o.z); PKMAX(a0.w, o.w);
        o.x = __shfl_xor(a0.x, 32); o.y = __shfl_xor(a0.y, 32);
        o.z = __shfl_xor(a0.z, 32); o.w = __shfl_xor(a0.w, 32);
        PKMAX(a0.x, o.x); PKMAX(a0.y, o.y);
        PKMAX(a0.z, o.z); PKMAX(a0.w, o.w);
    }
    if (lane < 16)
        *(uint4*)((char*)neigh + (((size_t)node << 8) | ((unsigned)lane << 4))) = a0;
}

// ---------------- merge: fm = exp(M-20)/S, then @ Wr + br ----------------
__global__ __launch_bounds__(256) void softmax_merge(
    const float* __restrict__ pm, const float* __restrict__ ps,
    const float* __restrict__ Wr, const float* __restrict__ brv,
    float* __restrict__ out)
{
    const int g = blockIdx.x;
    const int j = threadIdx.x;

    float M = pm[(size_t)g * HID + j];
    float S = ps[(size_t)g * HID + j];
    float fm = (S > 0.f) ? __expf(M - ESHIFT) / S : 0.f;

    float p0 = fm * Wr[j * 2 + 0];
    float p1 = fm * Wr[j * 2 + 1];
#pragma unroll
    for (int off = 32; off > 0; off >>= 1) {
        p0 += __shfl_down(p0, off);
        p1 += __shfl_down(p1, off);
    }
    __shared__ float red[8];
    int wv = j >> 6, ln = j & 63;
    if (ln == 0) { red[wv * 2] = p0; red[wv * 2 + 1] = p1; }
    __syncthreads();
    if (j == 0) out[g * 2 + 0] = red[0] + red[2] + red[4] + red[6] + brv[0];
    if (j == 1) out[g * 2 + 1] = red[1] + red[3] + red[5] + red[7] + brv[1];
}

// ---------------- launcher ----------------
extern "C" void kernel_launch(void* const* d_in, const int* in_sizes, int n_in,
                              void* d_out, int out_size, void* d_ws, size_t ws_size,
                              hipStream_t stream)
{
    const float* x      = (const float*)d_in[0];
    const float* W_pool = (const float*)d_in[1];
    const float* b_pool = (const float*)d_in[2];
    const float* W_self = (const float*)d_in[3];
    const float* W_neigh= (const float*)d_in[4];
    const float* b_sage = (const float*)d_in[5];
    const float* W1     = (const float*)d_in[6];
    const float* b1     = (const float*)d_in[7];
    const float* W2     = (const float*)d_in[8];
    const float* b2     = (const float*)d_in[9];
    const float* Wr     = (const float*)d_in[10];
    const float* br     = (const float*)d_in[11];
    const int*   src    = (const int*)d_in[12];
    const int*   dst    = (const int*)d_in[13];
    const int*   gid    = (const int*)d_in[14];

    const int Nn = N_NODES, E = N_EDGES;
    char* ws = (char*)d_ws;

    // ws layout (unchanged; pairs doubles as GEMM dummy-store sink, dead
    // after bucket_sort):
    unsigned short* xh    = (unsigned short*)(ws + 0);
    unsigned short* m_buf = (unsigned short*)(ws + 25600000);
    unsigned short* neigh = (unsigned short*)(ws + 51200000);
    int2*           pairs = (int2*)(ws + 76800000);
    int*            btot  = (int*)(ws + 89600000);
    int*            bstart= btot + NB2;
    int*            cursor= bstart + NB2 + 1;
    float*          pm    = (float*)(ws + 90000000);
    float*          ps    = pm + (size_t)N_GRAPHS * HID;
    int*            offs  = (int*)(ws + 91000000);
    int*            csr_src = (int*)(ws + 91500000);
    unsigned short* h1    = (unsigned short*)(ws + 102400000);
    unsigned short* h2    = (unsigned short*)(ws + 153600000);
    unsigned short* dummy = (unsigned short*)pairs;

    char* srcws = (char*)(void*)src;
    unsigned short* wpool_h = (unsigned short*)(srcws + 0);
    unsigned short* wpool_l = wpool_h + 128 * 128;
    unsigned short* wsage_h = wpool_l + 128 * 128;
    unsigned short* wsage_l = wsage_h + 256 * 256;
    unsigned short* w1_h    = wsage_l + 256 * 256;
    unsigned short* w1_l    = w1_h + 256 * 256;
    unsigned short* w2_h    = w1_l + 256 * 256;
    unsigned short* w2_l    = w2_h + 256 * 256;

    dim3 blk(256);
    const int pchunks = (E + 4095) / 4096;    // 391

    hipMemsetAsync(btot, 0, NB2 * sizeof(int), stream);
    hipMemsetAsync(pm, 0, (size_t)2 * N_GRAPHS * HID * sizeof(float), stream);

    // fused prep: x -> fp16 plane + bucket histogram (XHB + 391 blocks)
    prep_xh_count<<<dim3(XHB + pchunks), blk, 0, stream>>>(
        x, xh, Nn * IN_DIM, dst, btot, E);

    scan_b<<<dim3(1), blk, 0, stream>>>(btot, bstart, cursor, E);
    part_scatter<<<dim3(pchunks), blk, 0, stream>>>(src, dst, cursor, pairs, E);

    // src consumed by part_scatter: weight planes overwrite it now (1 launch)
    w_split_all<<<dim3(832), blk, 0, stream>>>(
        W_pool, W_self, W_neigh, W1, W2, (unsigned short*)srcws);

    bucket_sort<<<dim3(NB2), blk, 0, stream>>>(pairs, bstart, csr_src, offs, Nn, E);

    // GEMM0: m = relu(x @ W_pool + b_pool) -> fp16 [N,128] (B-stationary)
    gemm_bstat128<<<dim3(256), dim3(512), 0, stream>>>(
        xh, wpool_h, wpool_l, b_pool, m_buf, dummy, Nn);

    // neigh = segment-max of m
    csr_max_agg_h<<<dim3((Nn * 64 + 255) / 256), blk, 0, stream>>>(
        m_buf, csr_src, offs, neigh, Nn);

    // h1 = relu([x|neigh] @ [W_self;W_neigh] + b_sage) -> fp16 (B-stationary)
    gemm_bstat<<<dim3(256), dim3(512), 0, stream>>>(
        xh, neigh, 128, wsage_h, wsage_l, b_sage, h1, dummy, Nn);

    // h2 = relu(h1 @ W1 + b1) -> fp16 (B-stationary)
    gemm_bstat<<<dim3(256), dim3(512), 0, stream>>>(
        h1, h1, 256, w1_h, w1_l, b1, h2, dummy, Nn);

    // GEMM3 fused: softmax partials straight from the accumulators
    gemm_bstat_sm<<<dim3(256), dim3(512), 0, stream>>>(
        h2, w2_h, w2_l, b2, gid, pm, ps, Nn);

    // merge + final linear -> [256,2]
    softmax_merge<<<dim3(N_GRAPHS), blk, 0, stream>>>(pm, ps, Wr, br, (float*)d_out);
}

// Round 10
// 395.343 us; speedup vs baseline: 1.0769x; 1.0463x over previous
//
#include <hip/hip_runtime.h>

// ---------------- problem constants ----------------
#define N_NODES  100000
#define N_EDGES  1600000
#define IN_DIM   128
#define HID      256
#define N_GRAPHS 256
#define ESHIFT   20.0f    // exp shift: final = exp(M-20)/sum(exp(h-20))
#define BSH      7        // dst-tile shift: bucket = dst >> 7 (128 nodes)
#define NB2      782      // ceil(100000/128)
#define XHB      12500    // x_to_h blocks in fused prep kernel

typedef _Float16 f16x8 __attribute__((ext_vector_type(8)));
typedef float f32x16 __attribute__((ext_vector_type(16)));
#define MFMA16(a, b, c) __builtin_amdgcn_mfma_f32_32x32x16_f16((a), (b), (c), 0, 0, 0)

// packed fp16 max (values are post-ReLU >= 0, finite)
#define PKMAX(a, b) asm("v_pk_max_f16 %0, %0, %1" : "+v"(a) : "v"(b))

#define BARX() __builtin_amdgcn_s_barrier()
#define WAITVM(N) asm volatile("s_waitcnt vmcnt(" #N ")" ::: "memory")

static __device__ __forceinline__ unsigned short f2h_bits(float f) {
    _Float16 h = (_Float16)f;
    return __builtin_bit_cast(unsigned short, h);
}
static __device__ __forceinline__ float h2f(unsigned short b) {
    return (float)__builtin_bit_cast(_Float16, b);
}

// ---------------- fused prep: x -> fp16 plane  +  bucket histogram ----------
__global__ __launch_bounds__(256) void prep_xh_count(
    const float* __restrict__ x, unsigned short* __restrict__ xh, int nx,
    const int* __restrict__ dst, int* __restrict__ btot, int E)
{
    __shared__ int sh[NB2];
    const int t = threadIdx.x;
    if ((int)blockIdx.x < XHB) {
        int i = (blockIdx.x * 256 + t) * 4;
        if (i < nx) {
            float4 v = *(const float4*)&x[i];
            ushort4 h;
            h.x = f2h_bits(v.x); h.y = f2h_bits(v.y);
            h.z = f2h_bits(v.z); h.w = f2h_bits(v.w);
            *(ushort4*)&xh[i] = h;
        }
        return;                      // block-uniform: no barrier divergence
    }
    for (int i = t; i < NB2; i += 256) sh[i] = 0;
    __syncthreads();
    int base = (blockIdx.x - XHB) * 4096 + t;
#pragma unroll
    for (int i = 0; i < 16; ++i) {
        int e = base + i * 256;
        if (e < E) atomicAdd(&sh[dst[e] >> BSH], 1);
    }
    __syncthreads();
    for (int i = t; i < NB2; i += 256)
        if (sh[i]) atomicAdd(&btot[i], sh[i]);
}

// ---------------- fused weight transpose + fp16 hi/lo split (1 launch) -----
static __device__ __forceinline__ void wsplit_seg(
    const float* __restrict__ Wa, const float* __restrict__ Wb, int K1,
    int K, int N, unsigned short* __restrict__ hi, unsigned short* __restrict__ lo,
    int idx)
{
    if (idx >= K * N) return;
    int k = idx / N, n = idx - k * N;
    float w = (k < K1) ? Wa[(size_t)k * N + n] : Wb[(size_t)(k - K1) * N + n];
    unsigned short h = f2h_bits(w);
    unsigned short l = f2h_bits(w - h2f(h));
    hi[(size_t)n * K + k] = h;
    lo[(size_t)n * K + k] = l;
}

__global__ __launch_bounds__(256) void w_split_all(
    const float* __restrict__ Wp, const float* __restrict__ Ws,
    const float* __restrict__ Wn, const float* __restrict__ W1,
    const float* __restrict__ W2, unsigned short* __restrict__ base)
{
    const int blk = blockIdx.x, tid = threadIdx.x;
    unsigned short* wpool_h = base;
    unsigned short* wpool_l = wpool_h + 16384;
    unsigned short* wsage_h = wpool_l + 16384;
    unsigned short* wsage_l = wsage_h + 65536;
    unsigned short* w1_h    = wsage_l + 65536;
    unsigned short* w1_l    = w1_h + 65536;
    unsigned short* w2_h    = w1_l + 65536;
    unsigned short* w2_l    = w2_h + 65536;
    if (blk < 64)
        wsplit_seg(Wp, Wp, 128, 128, 128, wpool_h, wpool_l, blk * 256 + tid);
    else if (blk < 320)
        wsplit_seg(Ws, Wn, 128, 256, 256, wsage_h, wsage_l, (blk - 64) * 256 + tid);
    else if (blk < 576)
        wsplit_seg(W1, W1, 256, 256, 256, w1_h, w1_l, (blk - 320) * 256 + tid);
    else
        wsplit_seg(W2, W2, 256, 256, 256, w2_h, w2_l, (blk - 576) * 256 + tid);
}

// ---------------- B-stationary streaming GEMM (K=256, N=256) ----------------
static __device__ __forceinline__ void stage_tile64(
    const unsigned short* __restrict__ A1, const unsigned short* __restrict__ A2,
    int K1, int M, int r0g, short* bufb, int wave, int lane)
{
    const int l5 = lane >> 5;
    const int s  = lane & 31;
#pragma unroll
    for (int i = 0; i < 4; ++i) {
        const int p    = wave * 4 + i;          // row-pair index 0..31
        const int rloc = 2 * p + l5;            // 0..63
        int row = r0g + rloc; if (row >= M) row = M - 1;
        const int c8 = ((s ^ ((2 * i + l5) & 7)) << 3);  // pre-swizzled src k
        const unsigned short* sp = (c8 < K1)
            ? A1 + (size_t)row * K1 + c8
            : A2 + (size_t)row * (256 - K1) + (c8 - K1);
        __builtin_amdgcn_global_load_lds(sp, bufb + p * 512, 16, 0, 0);
    }
}

__global__ __launch_bounds__(512, 2) void gemm_bstat(
    const unsigned short* __restrict__ A1, const unsigned short* __restrict__ A2,
    int K1,
    const unsigned short* __restrict__ Wh, const unsigned short* __restrict__ Wl,
    const float* __restrict__ bias, unsigned short* __restrict__ C,
    unsigned short* __restrict__ dummy, int M)
{
    __shared__ __align__(16) short buf[2][64][256];   // 64KB

    const int tid = threadIdx.x, wave = tid >> 6, lane = tid & 63;
    const int lm = lane & 31, hib = lane >> 5;
    const int col = wave * 32 + lm;
    const int hi8 = hib * 8;

    f16x8 Bh[16], Bl[16];
#pragma unroll
    for (int k = 0; k < 16; ++k) {
        const size_t o = (size_t)col * 256 + k * 16 + hi8;
        Bh[k] = *(const f16x8*)(Wh + o);
        Bl[k] = *(const f16x8*)(Wl + o);
    }

    const int nt = (M + 63) >> 6;
    const int G = gridDim.x, b = blockIdx.x;
    const int q = nt / G, r = nt % G;
    const int t0  = b * q + (b < r ? b : r);
    const int ntl = q + (b < r ? 1 : 0);

    const int rq    = (lm >> 1) & 3;
    const int abase = lm * 512 + ((hib ^ (lm & 1)) << 4);
    const float bv  = bias[col];
    const int rb    = 4 * hib;

    stage_tile64(A1, A2, K1, M, t0 << 6, &buf[0][0][0], wave, lane);
    if (ntl > 1)
        stage_tile64(A1, A2, K1, M, (t0 + 1) << 6, &buf[1][0][0], wave, lane);

    for (int t = 0; t < ntl; ++t) {
        if (t == 0) { if (ntl > 1) WAITVM(4); else WAITVM(0); }
        else if (t + 1 < ntl) WAITVM(36);
        else WAITVM(32);
        BARX();

        f32x16 acc0, acc1;
#pragma unroll
        for (int i = 0; i < 16; ++i) { acc0[i] = 0.f; acc1[i] = 0.f; }
        const char* lb = (const char*)&buf[t & 1][0][0];
#pragma unroll
        for (int k = 0; k < 16; ++k) {
            const int koff = ((k ^ rq) << 5);
            f16x8 a0 = *(const f16x8*)(lb + abase + koff);
            f16x8 a1 = *(const f16x8*)(lb + abase + koff + 16384);
            acc0 = MFMA16(a0, Bh[k], acc0);
            acc1 = MFMA16(a1, Bh[k], acc1);
            acc0 = MFMA16(a0, Bl[k], acc0);
            acc1 = MFMA16(a1, Bl[k], acc1);
        }
        BARX();

        // prefetch first (HBM latency hides under store issue), then exactly
        // 32 stores (clamped rows -> dummy) so the in-flight count is fixed.
        if (t + 2 < ntl)
            stage_tile64(A1, A2, K1, M, (t0 + t + 2) << 6,
                         &buf[t & 1][0][0], wave, lane);
        const int r0g = (t0 + t) << 6;
#pragma unroll
        for (int reg = 0; reg < 16; ++reg) {
            const int rr0 = r0g + (reg & 3) + 8 * (reg >> 2) + rb;
            const int rr1 = rr0 + 32;
            unsigned short* d0 = (rr0 < M) ? C + (size_t)rr0 * 256 + col : dummy + tid;
            unsigned short* d1 = (rr1 < M) ? C + (size_t)rr1 * 256 + col : dummy + tid;
            *d0 = f2h_bits(fmaxf(acc0[reg] + bv, 0.f));
            *d1 = f2h_bits(fmaxf(acc1[reg] + bv, 0.f));
        }
    }
}

// ---------------- B-stationary GEMM0 (K=128, N=128) -------------------------
static __device__ __forceinline__ void stage_tile64_k128(
    const unsigned short* __restrict__ A, int M, int r0g,
    short* bufb, int wave, int lane)
{
#pragma unroll
    for (int p = 0; p < 2; ++p) {
        const int rl = p * 32 + wave * 4 + (lane >> 4);   // local row 0..63
        int row = r0g + rl; if (row >= M) row = M - 1;
        const int ch = (lane & 15) ^ (rl & 7);            // pre-swizzled chunk
        __builtin_amdgcn_global_load_lds(
            A + (size_t)row * 128 + ch * 8,
            bufb + p * 4096 + wave * 512, 16, 0, 0);
    }
}

__global__ __launch_bounds__(512, 2) void gemm_bstat128(
    const unsigned short* __restrict__ A,
    const unsigned short* __restrict__ Wh, const unsigned short* __restrict__ Wl,
    const float* __restrict__ bias, unsigned short* __restrict__ C,
    unsigned short* __restrict__ dummy, int M)
{
    __shared__ __align__(16) short buf[2][64][128];   // 32KB

    const int tid = threadIdx.x, wave = tid >> 6, lane = tid & 63;
    const int lm = lane & 31, hib = lane >> 5;
    const int colT = wave & 3;
    const int rw   = (wave >> 2) * 32;
    const int col  = colT * 32 + lm;

    f16x8 Bh[8], Bl[8];
#pragma unroll
    for (int k = 0; k < 8; ++k) {
        const size_t o = (size_t)col * 128 + k * 16 + hib * 8;
        Bh[k] = *(const f16x8*)(Wh + o);
        Bl[k] = *(const f16x8*)(Wl + o);
    }

    const int nt = (M + 63) >> 6;
    const int G = gridDim.x, b = blockIdx.x;
    const int q = nt / G, r = nt % G;
    const int t0  = b * q + (b < r ? b : r);
    const int ntl = q + (b < r ? 1 : 0);

    const int ch0 = hib ^ (lm & 7);        // read-side swizzle base
    const float bv = bias[col];

    stage_tile64_k128(A, M, t0 << 6, &buf[0][0][0], wave, lane);
    if (ntl > 1)
        stage_tile64_k128(A, M, (t0 + 1) << 6, &buf[1][0][0], wave, lane);

    for (int t = 0; t < ntl; ++t) {
        if (t == 0) { if (ntl > 1) WAITVM(2); else WAITVM(0); }
        else if (t + 1 < ntl) WAITVM(18);
        else WAITVM(16);
        BARX();

        f32x16 acc;
#pragma unroll
        for (int i = 0; i < 16; ++i) acc[i] = 0.f;
        const char* lb = (const char*)&buf[t & 1][0][0] + (rw + lm) * 256;
#pragma unroll
        for (int k = 0; k < 8; ++k) {
            f16x8 a = *(const f16x8*)(lb + (((2 * k) ^ ch0) << 4));
            acc = MFMA16(a, Bh[k], acc);
            acc = MFMA16(a, Bl[k], acc);
        }
        BARX();

        if (t + 2 < ntl)
            stage_tile64_k128(A, M, (t0 + t + 2) << 6,
                              &buf[t & 1][0][0], wave, lane);
        const int r0g = (t0 + t) << 6;
#pragma unroll
        for (int reg = 0; reg < 16; ++reg) {
            const int rr = r0g + rw + (reg & 3) + 8 * (reg >> 2) + 4 * hib;
            unsigned short* d = (rr < M) ? C + (size_t)rr * 128 + col : dummy + tid;
            *d = f2h_bits(fmaxf(acc[reg] + bv, 0.f));
        }
    }
}

// ---------------- B-stationary GEMM3 + fused softmax partials ---------------
static __device__ __forceinline__ void sm_flush(
    int run_g, float run_s, float run_m, int gfirst, int col,
    float* sS, int* sM, float* ps, float* pm)
{
    if (run_g < 0) return;
    int slot = run_g - gfirst;
    if (slot < 8) {
        atomicAdd(&sS[slot * 256 + col], run_s);
        atomicMax(&sM[slot * 256 + col], __float_as_int(run_m));
    } else {
        atomicAdd(&ps[(size_t)run_g * HID + col], run_s);
        atomicMax((int*)&pm[(size_t)run_g * HID + col], __float_as_int(run_m));
    }
}

__global__ __launch_bounds__(512, 2) void gemm_bstat_sm(
    const unsigned short* __restrict__ A,
    const unsigned short* __restrict__ Wh, const unsigned short* __restrict__ Wl,
    const float* __restrict__ bias, const int* __restrict__ gid,
    float* __restrict__ pm, float* __restrict__ ps, int M)
{
    __shared__ __align__(16) short buf[2][64][256];   // 64KB
    __shared__ float sS[8 * 256];                     // 8KB exp-sums
    __shared__ int   sM[8 * 256];                     // 8KB maxes

    const int tid = threadIdx.x, wave = tid >> 6, lane = tid & 63;
    const int lm = lane & 31, hib = lane >> 5;
    const int col = wave * 32 + lm;
    const int hi8 = hib * 8;

    for (int i = tid; i < 2048; i += 512) { sS[i] = 0.f; sM[i] = 0; }

    f16x8 Bh[16], Bl[16];
#pragma unroll
    for (int k = 0; k < 16; ++k) {
        const size_t o = (size_t)col * 256 + k * 16 + hi8;
        Bh[k] = *(const f16x8*)(Wh + o);
        Bl[k] = *(const f16x8*)(Wl + o);
    }

    const int nt = (M + 63) >> 6;
    const int G = gridDim.x, b = blockIdx.x;
    const int q = nt / G, r = nt % G;
    const int t0  = b * q + (b < r ? b : r);
    const int ntl = q + (b < r ? 1 : 0);

    const int rq    = (lm >> 1) & 3;
    const int abase = lm * 512 + ((hib ^ (lm & 1)) << 4);
    const float bv  = bias[col];
    const int rb    = 4 * hib;
    const int gfirst = gid[t0 << 6];

    stage_tile64(A, A, 256, M, t0 << 6, &buf[0][0][0], wave, lane);
    if (ntl > 1)
        stage_tile64(A, A, 256, M, (t0 + 1) << 6, &buf[1][0][0], wave, lane);

    int run_g = -1; float run_s = 0.f, run_m = 0.f;

    for (int t = 0; t < ntl; ++t) {
        if (t + 1 < ntl) WAITVM(4); else WAITVM(0);
        BARX();

        // issue the tile's gid load early; latency hides under MFMA loop
        const int r0g = (t0 + t) << 6;
        int gr = r0g + lane; if (gr >= M) gr = M - 1;
        int gv = gid[gr];
        asm volatile("" :: "v"(gv));     // pin issue point (rule 17)

        f32x16 acc0, acc1;
#pragma unroll
        for (int i = 0; i < 16; ++i) { acc0[i] = 0.f; acc1[i] = 0.f; }
        const char* lb = (const char*)&buf[t & 1][0][0];
#pragma unroll
        for (int k = 0; k < 16; ++k) {
            const int koff = ((k ^ rq) << 5);
            f16x8 a0 = *(const f16x8*)(lb + abase + koff);
            f16x8 a1 = *(const f16x8*)(lb + abase + koff + 16384);
            acc0 = MFMA16(a0, Bh[k], acc0);
            acc1 = MFMA16(a1, Bh[k], acc1);
            acc0 = MFMA16(a0, Bl[k], acc0);
            acc1 = MFMA16(a1, Bl[k], acc1);
        }
        BARX();

        // prefetch next-next tile, then drain gv (stage t+2 stays in flight)
        if (t + 2 < ntl) {
            stage_tile64(A, A, 256, M, (t0 + t + 2) << 6,
                         &buf[t & 1][0][0], wave, lane);
            WAITVM(4);
        } else {
            WAITVM(0);
        }

        const int gT0 = __shfl(gv, 0);
        const int gT1 = __shfl(gv, 63);
        if (gT0 == gT1) {
            // fast path: whole tile one graph (wave-uniform branch)
            if (gT0 != run_g) {
                sm_flush(run_g, run_s, run_m, gfirst, col, sS, sM, ps, pm);
                run_g = gT0; run_s = 0.f; run_m = 0.f;
            }
#pragma unroll
            for (int sub = 0; sub < 2; ++sub) {
                const f32x16& a = sub ? acc1 : acc0;
#pragma unroll
                for (int reg = 0; reg < 16; ++reg) {
                    const int rrow = r0g + sub * 32 + (reg & 3) + 8 * (reg >> 2) + rb;
                    float v = fmaxf(a[reg] + bv, 0.f);
                    bool ok = rrow < M;
                    run_s += ok ? __expf(v - ESHIFT) : 0.f;
                    run_m = ok ? fmaxf(run_m, v) : run_m;
                }
            }
        } else {
            // slow path: graph boundary inside tile; g via shfl (no VMEM)
#pragma unroll
            for (int sub = 0; sub < 2; ++sub) {
                const f32x16& a = sub ? acc1 : acc0;
#pragma unroll
                for (int reg = 0; reg < 16; ++reg) {
                    const int roff = sub * 32 + (reg & 3) + 8 * (reg >> 2) + rb;
                    const int rrow = r0g + roff;
                    int g = __shfl(gv, roff);
                    if (rrow >= M) continue;
                    float v = fmaxf(a[reg] + bv, 0.f);
                    if (g != run_g) {
                        sm_flush(run_g, run_s, run_m, gfirst, col, sS, sM, ps, pm);
                        run_g = g; run_s = 0.f; run_m = 0.f;
                    }
                    run_s += __expf(v - ESHIFT);
                    run_m = fmaxf(run_m, v);
                }
            }
        }
    }

    sm_flush(run_g, run_s, run_m, gfirst, col, sS, sM, ps, pm);
    __syncthreads();

    int lastrow = ((t0 + ntl) << 6) - 1; if (lastrow >= M) lastrow = M - 1;
    int span = gid[lastrow] - gfirst + 1; if (span > 8) span = 8;
    for (int i = tid; i < span * 256; i += 512) {
        float vs = sS[i];
        if (vs > 0.f) {
            int g = gfirst + (i >> 8), c = i & 255;
            atomicAdd(&ps[(size_t)g * HID + c], vs);
            atomicMax((int*)&pm[(size_t)g * HID + c], sM[i]);
        }
    }
}

// ---------------- edge pipeline: scan -> partition -> bucket sort -----------
__global__ __launch_bounds__(256) void scan_b(
    const int* __restrict__ btot, int* __restrict__ bstart,
    int* __restrict__ cursor, int total)
{
    __shared__ int sh[256];
    const int t = threadIdx.x;
    int a[4];
    int s = 0;
#pragma unroll
    for (int i = 0; i < 4; ++i) {
        int idx = t * 4 + i;
        a[i] = (idx < NB2) ? btot[idx] : 0;
        s += a[i];
    }
    sh[t] = s;
    __syncthreads();
    for (int off = 1; off < 256; off <<= 1) {
        int v = (t >= off) ? sh[t - off] : 0;
        __syncthreads();
        if (t >= off) sh[t] += v;
        __syncthreads();
    }
    int run = (t > 0) ? sh[t - 1] : 0;
#pragma unroll
    for (int i = 0; i < 4; ++i) {
        int idx = t * 4 + i;
        if (idx < NB2) { bstart[idx] = run; cursor[idx] = run; }
        run += a[i];
    }
    if (t == 0) bstart[NB2] = total;
}

__global__ __launch_bounds__(256) void part_scatter(
    const int* __restrict__ src, const int* __restrict__ dst,
    int* __restrict__ cursor, int2* __restrict__ pairs, int E)
{
    __shared__ int cnt[NB2], goff[NB2], fill[NB2];
    const int t = threadIdx.x;
    const int base = blockIdx.x * 4096;
    for (int i = t; i < NB2; i += 256) { cnt[i] = 0; fill[i] = 0; }
    __syncthreads();
    int myd[16];
#pragma unroll
    for (int i = 0; i < 16; ++i) {
        int e = base + t + i * 256;
        myd[i] = (e < E) ? dst[e] : -1;
        if (myd[i] >= 0) atomicAdd(&cnt[myd[i] >> BSH], 1);
    }
    __syncthreads();
    for (int i = t; i < NB2; i += 256)
        goff[i] = cnt[i] ? atomicAdd(&cursor[i], cnt[i]) : 0;
    __syncthreads();
#pragma unroll
    for (int i = 0; i < 16; ++i) {
        int e = base + t + i * 256;
        if (myd[i] >= 0) {
            int b = myd[i] >> BSH;
            int r = atomicAdd(&fill[b], 1);
            pairs[goff[b] + r] = make_int2(myd[i], src[e]);
        }
    }
}

__global__ __launch_bounds__(256) void bucket_sort(
    const int2* __restrict__ pairs, const int* __restrict__ bstart,
    int* __restrict__ csr_src, int* __restrict__ offs, int Nn, int E)
{
    __shared__ int cnt[128], off[128];
    const int b = blockIdx.x;
    const int t = threadIdx.x;
    const int lo = bstart[b], hi = bstart[b + 1];
    if (t < 128) cnt[t] = 0;
    __syncthreads();
    for (int e = lo + t; e < hi; e += 256)
        atomicAdd(&cnt[pairs[e].x & 127], 1);
    __syncthreads();
    if (t == 0) {
        int s = 0;
        for (int i = 0; i < 128; ++i) { off[i] = s; s += cnt[i]; }
    }
    __syncthreads();
    if (t < 128) {
        int node = (b << BSH) + t;
        if (node < Nn) offs[node] = lo + off[t];
        cnt[t] = off[t];          // reuse as fill cursor
    }
    if (b == NB2 - 1 && t == 0) offs[Nn] = E;
    __syncthreads();
    for (int e = lo + t; e < hi; e += 256) {
        int2 p = pairs[e];
        int r = atomicAdd(&cnt[p.x & 127], 1);
        csr_src[lo + r] = p.y;
    }
}

// ---------------- CSR max aggregation over fp16 m, one wave per node --------
// At its structural floor: random gather, fabric-limited (~3.8 TB/s L2-miss
// service, ~7.5 TB/s effective delivered). ILP probe (R6) moved it only -2us.
__global__ __launch_bounds__(256) void csr_max_agg_h(
    const unsigned short* __restrict__ m, const int* __restrict__ csr_src,
    const int* __restrict__ offs, unsigned short* __restrict__ neigh, int Nn)
{
    const int node = (blockIdx.x * 256 + threadIdx.x) >> 6;
    const int lane = threadIdx.x & 63;
    if (node >= Nn) return;
    const int e0  = offs[node];
    const int end = offs[node + 1];
    const char* mc = (const char*)m;

    uint4 a0 = make_uint4(0u, 0u, 0u, 0u);
    uint4 a1 = a0, a2 = a0, a3 = a0;
    if (end > e0) {
        const unsigned fo = (unsigned)(lane & 15) << 4;   // feature byte off
        const int sub = lane >> 4;                        // row slot 0..3
        for (int base = e0; base < end; base += 64) {
            int ee = base + lane;
            int sl = csr_src[ee < end ? ee : (end - 1)];  // coalesced, clamped
            int cnt = end - base; if (cnt > 64) cnt = 64;
            int iters = (cnt + 3) >> 2;                   // 1..16
            for (int j = 0; j < iters; j += 4) {
                int j1 = j + 1 < 16 ? j + 1 : 15;
                int j2 = j + 2 < 16 ? j + 2 : 15;
                int j3 = j + 3 < 16 ? j + 3 : 15;
                int s0 = __shfl(sl, (j  << 2) | sub);
                int s1 = __shfl(sl, (j1 << 2) | sub);
                int s2 = __shfl(sl, (j2 << 2) | sub);
                int s3 = __shfl(sl, (j3 << 2) | sub);
                uint4 v0 = *(const uint4*)(mc + (((unsigned)s0 << 8) | fo));
                uint4 v1 = *(const uint4*)(mc + (((unsigned)s1 << 8) | fo));
                uint4 v2 = *(const uint4*)(mc + (((unsigned)s2 << 8) | fo));
                uint4 v3 = *(const uint4*)(mc + (((unsigned)s3 << 8) | fo));
                PKMAX(a0.x, v0.x); PKMAX(a0.y, v0.y);
                PKMAX(a0.z, v0.z); PKMAX(a0.w, v0.w);
                PKMAX(a1.x, v1.x); PKMAX(a1.y, v1.y);
                PKMAX(a1.z, v1.z); PKMAX(a1.w, v1.w);
                PKMAX(a2.x, v2.x); PKMAX(a2.y, v2.y);
                PKMAX(a2.z, v2.z); PKMAX(a2.w, v2.w);
                PKMAX(a3.x, v3.x); PKMAX(a3.y, v3.y);
                PKMAX(a3.z, v3.z); PKMAX(a3.w, v3.w);
            }
        }
        // merge the 4 unroll accumulators
        PKMAX(a0.x, a1.x); PKMAX(a0.y, a1.y);
        PKMAX(a0.z, a1.z); PKMAX(a0.w, a1.w);
        PKMAX(a2.x, a3.x); PKMAX(a2.y, a3.y);
        PKMAX(a2.z, a3.z); PKMAX(a2.w, a3.w);
        PKMAX(a0.x, a2.x); PKMAX(a0.y, a2.y);
        PKMAX(a0.z, a2.z); PKMAX(a0.w, a2.w);
        // reduce the 4 row-substreams (lane>>4 groups): xor16 then xor32
        uint4 o;
        o.x = __shfl_xor(a0.x, 16); o.y = __shfl_xor(a0.y, 16);
        o.z = __shfl_xor(a0.z, 16); o.w = __shfl_xor(a0.w, 16);
        PKMAX(a0.x, o.x); PKMAX(a0.y, o.y);
        PKMAX(a0.z, o.z); PKMAX(a0.w, o.w);
        o.x = __shfl_xor(a0.x, 32); o.y = __shfl_xor(a0.y, 32);
        o.z = __shfl_xor(a0.z, 32); o.w = __shfl_xor(a0.w, 32);
        PKMAX(a0.x, o.x); PKMAX(a0.y, o.y);
        PKMAX(a0.z, o.z); PKMAX(a0.w, o.w);
    }
    if (lane < 16)
        *(uint4*)((char*)neigh + (((size_t)node << 8) | ((unsigned)lane << 4))) = a0;
}

// ---------------- merge: fm = exp(M-20)/S, then @ Wr + br ----------------
__global__ __launch_bounds__(256) void softmax_merge(
    const float* __restrict__ pm, const float* __restrict__ ps,
    const float* __restrict__ Wr, const float* __restrict__ brv,
    float* __restrict__ out)
{
    const int g = blockIdx.x;
    const int j = threadIdx.x;

    float M = pm[(size_t)g * HID + j];
    float S = ps[(size_t)g * HID + j];
    float fm = (S > 0.f) ? __expf(M - ESHIFT) / S : 0.f;

    float p0 = fm * Wr[j * 2 + 0];
    float p1 = fm * Wr[j * 2 + 1];
#pragma unroll
    for (int off = 32; off > 0; off >>= 1) {
        p0 += __shfl_down(p0, off);
        p1 += __shfl_down(p1, off);
    }
    __shared__ float red[8];
    int wv = j >> 6, ln = j & 63;
    if (ln == 0) { red[wv * 2] = p0; red[wv * 2 + 1] = p1; }
    __syncthreads();
    if (j == 0) out[g * 2 + 0] = red[0] + red[2] + red[4] + red[6] + brv[0];
    if (j == 1) out[g * 2 + 1] = red[1] + red[3] + red[5] + red[7] + brv[1];
}

// ---------------- launcher ----------------
extern "C" void kernel_launch(void* const* d_in, const int* in_sizes, int n_in,
                              void* d_out, int out_size, void* d_ws, size_t ws_size,
                              hipStream_t stream)
{
    const float* x      = (const float*)d_in[0];
    const float* W_pool = (const float*)d_in[1];
    const float* b_pool = (const float*)d_in[2];
    const float* W_self = (const float*)d_in[3];
    const float* W_neigh= (const float*)d_in[4];
    const float* b_sage = (const float*)d_in[5];
    const float* W1     = (const float*)d_in[6];
    const float* b1     = (const float*)d_in[7];
    const float* W2     = (const float*)d_in[8];
    const float* b2     = (const float*)d_in[9];
    const float* Wr     = (const float*)d_in[10];
    const float* br     = (const float*)d_in[11];
    const int*   src    = (const int*)d_in[12];
    const int*   dst    = (const int*)d_in[13];
    const int*   gid    = (const int*)d_in[14];

    const int Nn = N_NODES, E = N_EDGES;
    char* ws = (char*)d_ws;

    // ws layout (unchanged; pairs doubles as GEMM dummy-store sink, dead
    // after bucket_sort):
    unsigned short* xh    = (unsigned short*)(ws + 0);
    unsigned short* m_buf = (unsigned short*)(ws + 25600000);
    unsigned short* neigh = (unsigned short*)(ws + 51200000);
    int2*           pairs = (int2*)(ws + 76800000);
    int*            btot  = (int*)(ws + 89600000);
    int*            bstart= btot + NB2;
    int*            cursor= bstart + NB2 + 1;
    float*          pm    = (float*)(ws + 90000000);
    float*          ps    = pm + (size_t)N_GRAPHS * HID;
    int*            offs  = (int*)(ws + 91000000);
    int*            csr_src = (int*)(ws + 91500000);
    unsigned short* h1    = (unsigned short*)(ws + 102400000);
    unsigned short* h2    = (unsigned short*)(ws + 153600000);
    unsigned short* dummy = (unsigned short*)pairs;

    char* srcws = (char*)(void*)src;
    unsigned short* wpool_h = (unsigned short*)(srcws + 0);
    unsigned short* wpool_l = wpool_h + 128 * 128;
    unsigned short* wsage_h = wpool_l + 128 * 128;
    unsigned short* wsage_l = wsage_h + 256 * 256;
    unsigned short* w1_h    = wsage_l + 256 * 256;
    unsigned short* w1_l    = w1_h + 256 * 256;
    unsigned short* w2_h    = w1_l + 256 * 256;
    unsigned short* w2_l    = w2_h + 256 * 256;

    dim3 blk(256);
    const int pchunks = (E + 4095) / 4096;    // 391

    hipMemsetAsync(btot, 0, NB2 * sizeof(int), stream);
    hipMemsetAsync(pm, 0, (size_t)2 * N_GRAPHS * HID * sizeof(float), stream);

    // fused prep: x -> fp16 plane + bucket histogram (XHB + 391 blocks)
    prep_xh_count<<<dim3(XHB + pchunks), blk, 0, stream>>>(
        x, xh, Nn * IN_DIM, dst, btot, E);

    scan_b<<<dim3(1), blk, 0, stream>>>(btot, bstart, cursor, E);
    part_scatter<<<dim3(pchunks), blk, 0, stream>>>(src, dst, cursor, pairs, E);

    // src consumed by part_scatter: weight planes overwrite it now (1 launch)
    w_split_all<<<dim3(832), blk, 0, stream>>>(
        W_pool, W_self, W_neigh, W1, W2, (unsigned short*)srcws);

    bucket_sort<<<dim3(NB2), blk, 0, stream>>>(pairs, bstart, csr_src, offs, Nn, E);

    // GEMM0: m = relu(x @ W_pool + b_pool) -> fp16 [N,128] (B-stationary)
    gemm_bstat128<<<dim3(256), dim3(512), 0, stream>>>(
        xh, wpool_h, wpool_l, b_pool, m_buf, dummy, Nn);

    // neigh = segment-max of m
    csr_max_agg_h<<<dim3((Nn * 64 + 255) / 256), blk, 0, stream>>>(
        m_buf, csr_src, offs, neigh, Nn);

    // h1 = relu([x|neigh] @ [W_self;W_neigh] + b_sage) -> fp16 (B-stationary)
    gemm_bstat<<<dim3(256), dim3(512), 0, stream>>>(
        xh, neigh, 128, wsage_h, wsage_l, b_sage, h1, dummy, Nn);

    // h2 = relu(h1 @ W1 + b1) -> fp16 (B-stationary)
    gemm_bstat<<<dim3(256), dim3(512), 0, stream>>>(
        h1, h1, 256, w1_h, w1_l, b1, h2, dummy, Nn);

    // GEMM3 fused: softmax partials straight from the accumulators
    gemm_bstat_sm<<<dim3(256), dim3(512), 0, stream>>>(
        h2, w2_h, w2_l, b2, gid, pm, ps, Nn);

    // merge + final linear -> [256,2]
    softmax_merge<<<dim3(N_GRAPHS), blk, 0, stream>>>(pm, ps, Wr, br, (float*)d_out);
}